// Round 1
// baseline (221.033 us; speedup 1.0000x reference)
//
#include <hip/hip_runtime.h>
#include <math.h>

#define BB 2
#define LL 2048
#define MM 1024
#define DD 16
#define RR 64
#define NN 96
#define BLROWS (BB*LL)          // 4096
#define NCH 32                  // chunks
#define CLEN (LL/NCH)           // 64

// workspace layout (float offsets)
#define OFF_XP    0
#define OFF_DT    (OFF_XP + BLROWS*NN)            // 393216
#define OFF_WT    (OFF_DT + BLROWS*MM)            // + 4194304
#define OFF_DTWT  (OFF_WT + MM*NN)                // + 98304
#define OFF_A2    (OFF_DTWT + RR*MM)              // + 65536
#define OFF_HEND  (OFF_A2 + MM*DD)                // + 16384
#define OFF_DTSUM (OFF_HEND + NCH*BB*MM*DD)       // + 1048576
#define OFF_H0    (OFF_DTSUM + NCH*BB*MM)         // + 65536
// total = OFF_H0 + NCH*BB*MM*DD = 6930432 floats = 27.7 MB

#define LOG2E 1.44269504088896340736f

__device__ __forceinline__ float softplusf(float v) {
  return v > 20.f ? v : log1pf(expf(v));
}

// ---------------- prep: transposes + A2 = -exp(A_log)^T * log2e ----------------
__global__ __launch_bounds__(256) void k_prep(const float* __restrict__ W,
                                              const float* __restrict__ dtW,
                                              const float* __restrict__ A_log,
                                              float* __restrict__ ws) {
  int idx = blockIdx.x * 256 + threadIdx.x;
  if (idx < MM * NN) {
    int m = idx / NN, n = idx % NN;
    ws[OFF_WT + idx] = W[n * MM + m];
  } else if (idx < MM * NN + RR * MM) {
    int j = idx - MM * NN;
    int r = j / MM, m = j % MM;
    ws[OFF_DTWT + j] = dtW[m * RR + r];
  } else if (idx < MM * NN + RR * MM + MM * DD) {
    int j = idx - MM * NN - RR * MM;
    int m = j / DD, d = j % DD;
    ws[OFF_A2 + j] = -expf(A_log[d * MM + m]) * LOG2E;
  }
}

// ---------------- xp = x @ W^T  (4096 x 96, K=1024) ----------------
// grid 256 wgs (16 rows each), block 192: nt=t%24 (4 n's), rt=t/24 (rows rt, rt+8)
__global__ __launch_bounds__(192) void k_xp(const float* __restrict__ x,
                                            float* __restrict__ ws) {
  const float4* Wt4 = (const float4*)(ws + OFF_WT); // [m][24] float4
  float* xp = ws + OFF_XP;
  __shared__ float xs[16 * 1032];
  int bl0 = blockIdx.x * 16;
  const float4* xrow4 = (const float4*)(x + (size_t)bl0 * MM);
  for (int i = threadIdx.x; i < 4096; i += 192) {
    int r = i >> 8, c4 = i & 255;
    *(float4*)&xs[r * 1032 + c4 * 4] = xrow4[i];
  }
  __syncthreads();
  int nt = threadIdx.x % 24, rt = threadIdx.x / 24;
  float acc0x = 0.f, acc0y = 0.f, acc0z = 0.f, acc0w = 0.f;
  float acc1x = 0.f, acc1y = 0.f, acc1z = 0.f, acc1w = 0.f;
  for (int m4 = 0; m4 < 256; ++m4) {
    float4 xa = *(const float4*)&xs[rt * 1032 + m4 * 4];
    float4 xb = *(const float4*)&xs[(rt + 8) * 1032 + m4 * 4];
    float xaA[4] = {xa.x, xa.y, xa.z, xa.w};
    float xbA[4] = {xb.x, xb.y, xb.z, xb.w};
#pragma unroll
    for (int j = 0; j < 4; ++j) {
      float4 w = Wt4[(m4 * 4 + j) * 24 + nt];
      acc0x += xaA[j] * w.x; acc0y += xaA[j] * w.y;
      acc0z += xaA[j] * w.z; acc0w += xaA[j] * w.w;
      acc1x += xbA[j] * w.x; acc1y += xbA[j] * w.y;
      acc1z += xbA[j] * w.z; acc1w += xbA[j] * w.w;
    }
  }
  int row0 = bl0 + rt, row1 = bl0 + rt + 8;
  *(float4*)&xp[row0 * NN + nt * 4] = make_float4(acc0x, acc0y, acc0z, acc0w);
  *(float4*)&xp[row1 * NN + nt * 4] = make_float4(acc1x, acc1y, acc1z, acc1w);
}

// ---------------- dt = softplus(xp[:, :64] @ dtW^T + b)  (4096 x 1024, K=64) ----------------
// grid 256 wgs (16 rows), block 256: thread t owns 4 m's (t*4..t*4+3), all 16 rows
__global__ __launch_bounds__(256) void k_dt(const float* __restrict__ dtb,
                                            float* __restrict__ ws) {
  const float* xp = ws + OFF_XP;
  const float4* dtWt4 = (const float4*)(ws + OFF_DTWT); // [r][256] float4
  float* dt = ws + OFF_DT;
  __shared__ float xs[16 * 64];
  int bl0 = blockIdx.x * 16;
  int t = threadIdx.x;
  {
    int r = t >> 4, c4 = t & 15;
    *(float4*)&xs[r * 64 + c4 * 4] = *(const float4*)&xp[(bl0 + r) * NN + c4 * 4];
  }
  __syncthreads();
  float acc[16][4] = {};
#pragma unroll 4
  for (int r4 = 0; r4 < 16; ++r4) {
    float4 w0 = dtWt4[(r4 * 4 + 0) * 256 + t];
    float4 w1 = dtWt4[(r4 * 4 + 1) * 256 + t];
    float4 w2 = dtWt4[(r4 * 4 + 2) * 256 + t];
    float4 w3 = dtWt4[(r4 * 4 + 3) * 256 + t];
#pragma unroll
    for (int i = 0; i < 16; ++i) {
      float4 xv = *(const float4*)&xs[i * 64 + r4 * 4];
      acc[i][0] += xv.x * w0.x + xv.y * w1.x + xv.z * w2.x + xv.w * w3.x;
      acc[i][1] += xv.x * w0.y + xv.y * w1.y + xv.z * w2.y + xv.w * w3.y;
      acc[i][2] += xv.x * w0.z + xv.y * w1.z + xv.z * w2.z + xv.w * w3.z;
      acc[i][3] += xv.x * w0.w + xv.y * w1.w + xv.z * w2.w + xv.w * w3.w;
    }
  }
  float4 bv = *(const float4*)&dtb[t * 4];
#pragma unroll
  for (int i = 0; i < 16; ++i) {
    float4 o;
    o.x = softplusf(acc[i][0] + bv.x);
    o.y = softplusf(acc[i][1] + bv.y);
    o.z = softplusf(acc[i][2] + bv.z);
    o.w = softplusf(acc[i][3] + bv.w);
    *(float4*)&dt[(size_t)(bl0 + i) * MM + t * 4] = o;
  }
}

// ---------------- scan phase 1: per-chunk h_end and sum(dt) ----------------
// grid 256: wg -> (b, chunk c, m-quarter), block 256 (thread = m)
__global__ __launch_bounds__(256) void k_scan1(const float* __restrict__ x,
                                               float* __restrict__ ws) {
  const float* dt = ws + OFF_DT;
  const float* xp = ws + OFF_XP;
  const float* A2t = ws + OFF_A2;
  float* hend = ws + OFF_HEND;
  float* dtsum = ws + OFF_DTSUM;
  int wg = blockIdx.x;
  int mw = wg & 3, c = (wg >> 2) & 31, b = wg >> 7;
  int m = mw * 256 + threadIdx.x;
  float A2[DD], h[DD] = {};
#pragma unroll
  for (int k = 0; k < 4; ++k) {
    float4 v = *(const float4*)&A2t[m * DD + 4 * k];
    A2[4 * k] = v.x; A2[4 * k + 1] = v.y; A2[4 * k + 2] = v.z; A2[4 * k + 3] = v.w;
  }
  float S = 0.f;
  int l0 = c * CLEN;
  for (int l = l0; l < l0 + CLEN; ++l) {
    size_t idx = ((size_t)(b * LL + l)) * MM + m;
    float dtv = dt[idx];
    float xv = x[idx];
    S += dtv;
    const float* bc = &xp[(b * LL + l) * NN + RR];
    float Bv[DD];
#pragma unroll
    for (int k = 0; k < 4; ++k) {
      float4 v = *(const float4*)&bc[4 * k];
      Bv[4 * k] = v.x; Bv[4 * k + 1] = v.y; Bv[4 * k + 2] = v.z; Bv[4 * k + 3] = v.w;
    }
    float dtx = dtv * xv;
#pragma unroll
    for (int d = 0; d < DD; ++d)
      h[d] = exp2f(dtv * A2[d]) * h[d] + dtx * Bv[d];
  }
  size_t o = ((size_t)((c * BB + b) * MM + m)) * DD;
#pragma unroll
  for (int k = 0; k < 4; ++k)
    *(float4*)&hend[o + 4 * k] = make_float4(h[4 * k], h[4 * k + 1], h[4 * k + 2], h[4 * k + 3]);
  dtsum[(c * BB + b) * MM + m] = S;
}

// ---------------- scan phase 2: scan over chunks, emit h0 per chunk ----------------
__global__ __launch_bounds__(256) void k_scan2(float* __restrict__ ws) {
  int t = blockIdx.x * 256 + threadIdx.x; // 32768 threads
  int d = t & 15, m = (t >> 4) & 1023, b = t >> 14;
  const float* hend = ws + OFF_HEND;
  const float* dtsum = ws + OFF_DTSUM;
  float* h0 = ws + OFF_H0;
  float A2 = ws[OFF_A2 + m * DD + d];
  float h = 0.f;
  for (int c = 0; c < NCH; ++c) {
    size_t o = ((size_t)((c * BB + b) * MM + m)) * DD + d;
    h0[o] = h;
    float S = dtsum[(c * BB + b) * MM + m];
    h = exp2f(A2 * S) * h + hend[o];
  }
}

// ---------------- scan phase 3: recompute with correct h0, emit y * silu(z) ----------------
__global__ __launch_bounds__(256) void k_scan3(const float* __restrict__ x,
                                               const float* __restrict__ z,
                                               const float* __restrict__ Dp,
                                               float* __restrict__ out,
                                               float* __restrict__ ws) {
  const float* dt = ws + OFF_DT;
  const float* xp = ws + OFF_XP;
  const float* A2t = ws + OFF_A2;
  const float* h0w = ws + OFF_H0;
  int wg = blockIdx.x;
  int mw = wg & 3, c = (wg >> 2) & 31, b = wg >> 7;
  int m = mw * 256 + threadIdx.x;
  float A2[DD], h[DD];
#pragma unroll
  for (int k = 0; k < 4; ++k) {
    float4 v = *(const float4*)&A2t[m * DD + 4 * k];
    A2[4 * k] = v.x; A2[4 * k + 1] = v.y; A2[4 * k + 2] = v.z; A2[4 * k + 3] = v.w;
  }
  size_t o = ((size_t)((c * BB + b) * MM + m)) * DD;
#pragma unroll
  for (int k = 0; k < 4; ++k) {
    float4 v = *(const float4*)&h0w[o + 4 * k];
    h[4 * k] = v.x; h[4 * k + 1] = v.y; h[4 * k + 2] = v.z; h[4 * k + 3] = v.w;
  }
  float Dpm = Dp[m];
  int l0 = c * CLEN;
  for (int l = l0; l < l0 + CLEN; ++l) {
    size_t idx = ((size_t)(b * LL + l)) * MM + m;
    float dtv = dt[idx];
    float xv = x[idx];
    float zv = z[idx];
    const float* bc = &xp[(b * LL + l) * NN + RR];
    float Bv[DD], Cv[DD];
#pragma unroll
    for (int k = 0; k < 4; ++k) {
      float4 v = *(const float4*)&bc[4 * k];
      Bv[4 * k] = v.x; Bv[4 * k + 1] = v.y; Bv[4 * k + 2] = v.z; Bv[4 * k + 3] = v.w;
      float4 u = *(const float4*)&bc[DD + 4 * k];
      Cv[4 * k] = u.x; Cv[4 * k + 1] = u.y; Cv[4 * k + 2] = u.z; Cv[4 * k + 3] = u.w;
    }
    float dtx = dtv * xv;
    float y = 0.f;
#pragma unroll
    for (int d = 0; d < DD; ++d) {
      h[d] = exp2f(dtv * A2[d]) * h[d] + dtx * Bv[d];
      y += h[d] * Cv[d];
    }
    y += Dpm * xv;
    float sig = 1.f / (1.f + exp2f(-LOG2E * zv));
    out[idx] = y * zv * sig;
  }
}

extern "C" void kernel_launch(void* const* d_in, const int* in_sizes, int n_in,
                              void* d_out, int out_size, void* d_ws, size_t ws_size,
                              hipStream_t stream) {
  const float* x = (const float*)d_in[0];
  const float* z = (const float*)d_in[1];
  const float* W = (const float*)d_in[2];
  const float* dtW = (const float*)d_in[3];
  const float* dtb = (const float*)d_in[4];
  const float* A_log = (const float*)d_in[5];
  const float* Dp = (const float*)d_in[6];
  float* out = (float*)d_out;
  float* ws = (float*)d_ws;

  k_prep<<<704, 256, 0, stream>>>(W, dtW, A_log, ws);
  k_xp<<<256, 192, 0, stream>>>(x, ws);
  k_dt<<<256, 256, 0, stream>>>(dtb, ws);
  k_scan1<<<256, 256, 0, stream>>>(x, ws);
  k_scan2<<<128, 256, 0, stream>>>(ws);
  k_scan3<<<256, 256, 0, stream>>>(x, z, Dp, out, ws);
}

// Round 2
// 184.186 us; speedup vs baseline: 1.2001x; 1.2001x over previous
//
#include <hip/hip_runtime.h>
#include <math.h>

#define BB 2
#define LL 2048
#define MM 1024
#define DD 16
#define RR 64
#define NN 96
#define BLROWS (BB*LL)          // 4096
#define NCH 64                  // chunks
#define CLEN (LL/NCH)           // 32

// workspace layout (float offsets)
#define OFF_XP    0
#define OFF_DT    (OFF_XP + BLROWS*NN)            // 393216
#define OFF_WT    (OFF_DT + BLROWS*MM)            // + 4194304
#define OFF_DTWT  (OFF_WT + MM*NN)                // + 98304
#define OFF_A2    (OFF_DTWT + RR*MM)              // + 65536
#define OFF_HEND  (OFF_A2 + MM*DD)                // + 16384
#define OFF_DTSUM (OFF_HEND + NCH*BB*MM*DD)       // + 2097152
// total = OFF_DTSUM + NCH*BB*MM = 6995968 floats = 28.0 MB

#define LOG2E 1.44269504088896340736f

__device__ __forceinline__ float softplusf(float v) {
  return v > 20.f ? v : log1pf(expf(v));
}

// ---------------- prep: transposes + A2 = -exp(A_log)^T * log2e ----------------
__global__ __launch_bounds__(256) void k_prep(const float* __restrict__ W,
                                              const float* __restrict__ dtW,
                                              const float* __restrict__ A_log,
                                              float* __restrict__ ws) {
  int idx = blockIdx.x * 256 + threadIdx.x;
  if (idx < MM * NN) {
    int m = idx / NN, n = idx % NN;
    ws[OFF_WT + idx] = W[n * MM + m];
  } else if (idx < MM * NN + RR * MM) {
    int j = idx - MM * NN;
    int r = j / MM, m = j % MM;
    ws[OFF_DTWT + j] = dtW[m * RR + r];
  } else if (idx < MM * NN + RR * MM + MM * DD) {
    int j = idx - MM * NN - RR * MM;
    int m = j / DD, d = j % DD;
    ws[OFF_A2 + j] = -expf(A_log[d * MM + m]) * LOG2E;
  }
}

// ---------------- xp = x @ W^T  (4096 x 96, K=1024) ----------------
// grid 256 wgs (16 rows each), block 192: nt=t%24 (4 n's), rt=t/24 (rows rt, rt+8)
__global__ __launch_bounds__(192) void k_xp(const float* __restrict__ x,
                                            float* __restrict__ ws) {
  const float4* Wt4 = (const float4*)(ws + OFF_WT); // [m][24] float4
  float* xp = ws + OFF_XP;
  __shared__ float xs[16 * 1032];
  int bl0 = blockIdx.x * 16;
  const float4* xrow4 = (const float4*)(x + (size_t)bl0 * MM);
  for (int i = threadIdx.x; i < 4096; i += 192) {
    int r = i >> 8, c4 = i & 255;
    *(float4*)&xs[r * 1032 + c4 * 4] = xrow4[i];
  }
  __syncthreads();
  int nt = threadIdx.x % 24, rt = threadIdx.x / 24;
  float acc0x = 0.f, acc0y = 0.f, acc0z = 0.f, acc0w = 0.f;
  float acc1x = 0.f, acc1y = 0.f, acc1z = 0.f, acc1w = 0.f;
  for (int m4 = 0; m4 < 256; ++m4) {
    float4 xa = *(const float4*)&xs[rt * 1032 + m4 * 4];
    float4 xb = *(const float4*)&xs[(rt + 8) * 1032 + m4 * 4];
    float xaA[4] = {xa.x, xa.y, xa.z, xa.w};
    float xbA[4] = {xb.x, xb.y, xb.z, xb.w};
#pragma unroll
    for (int j = 0; j < 4; ++j) {
      float4 w = Wt4[(m4 * 4 + j) * 24 + nt];
      acc0x += xaA[j] * w.x; acc0y += xaA[j] * w.y;
      acc0z += xaA[j] * w.z; acc0w += xaA[j] * w.w;
      acc1x += xbA[j] * w.x; acc1y += xbA[j] * w.y;
      acc1z += xbA[j] * w.z; acc1w += xbA[j] * w.w;
    }
  }
  int row0 = bl0 + rt, row1 = bl0 + rt + 8;
  *(float4*)&xp[row0 * NN + nt * 4] = make_float4(acc0x, acc0y, acc0z, acc0w);
  *(float4*)&xp[row1 * NN + nt * 4] = make_float4(acc1x, acc1y, acc1z, acc1w);
}

// ---------------- dt = softplus(xp[:, :64] @ dtW^T + b)  (4096 x 1024, K=64) ----------------
// grid (MM/256)*(BLROWS/16) = 4*256 = 1024 wgs, block 256.
// tid: mt = t&63 (4 m's as one float4), rg = t>>6 (4 rows). acc[4][4] = 16 regs, no spill.
__global__ __launch_bounds__(256) void k_dt(const float* __restrict__ dtb,
                                            float* __restrict__ ws) {
  const float* xp = ws + OFF_XP;
  const float4* dtWt4 = (const float4*)(ws + OFF_DTWT); // [r][256] float4
  float* dt = ws + OFF_DT;
  __shared__ float xs[16 * 64];
  int mb = blockIdx.x & 3;
  int bl0 = (blockIdx.x >> 2) * 16;
  int t = threadIdx.x;
  {
    int r = t >> 4, c4 = t & 15;
    *(float4*)&xs[r * 64 + c4 * 4] = *(const float4*)&xp[(size_t)(bl0 + r) * NN + c4 * 4];
  }
  __syncthreads();
  int mt = t & 63, rg = t >> 6;
  int m4 = mb * 64 + mt;   // float4 index into m (0..255)
  float acc[4][4] = {};
  for (int k4 = 0; k4 < 16; ++k4) {
    float4 w0 = dtWt4[(k4 * 4 + 0) * 256 + m4];
    float4 w1 = dtWt4[(k4 * 4 + 1) * 256 + m4];
    float4 w2 = dtWt4[(k4 * 4 + 2) * 256 + m4];
    float4 w3 = dtWt4[(k4 * 4 + 3) * 256 + m4];
#pragma unroll
    for (int r = 0; r < 4; ++r) {
      float4 xv = *(const float4*)&xs[(rg * 4 + r) * 64 + k4 * 4];
      acc[r][0] += xv.x * w0.x + xv.y * w1.x + xv.z * w2.x + xv.w * w3.x;
      acc[r][1] += xv.x * w0.y + xv.y * w1.y + xv.z * w2.y + xv.w * w3.y;
      acc[r][2] += xv.x * w0.z + xv.y * w1.z + xv.z * w2.z + xv.w * w3.z;
      acc[r][3] += xv.x * w0.w + xv.y * w1.w + xv.z * w2.w + xv.w * w3.w;
    }
  }
  float4 bv = *(const float4*)&dtb[m4 * 4];
#pragma unroll
  for (int r = 0; r < 4; ++r) {
    float4 o;
    o.x = softplusf(acc[r][0] + bv.x);
    o.y = softplusf(acc[r][1] + bv.y);
    o.z = softplusf(acc[r][2] + bv.z);
    o.w = softplusf(acc[r][3] + bv.w);
    *(float4*)&dt[(size_t)(bl0 + rg * 4 + r) * MM + m4 * 4] = o;
  }
}

// ---------------- scan phase 1: per-chunk h_end and sum(dt) ----------------
// grid 4*NCH*BB = 512 wgs, block 256 (thread = m within quarter)
__global__ __launch_bounds__(256) void k_scan1(const float* __restrict__ x,
                                               float* __restrict__ ws) {
  const float* dt = ws + OFF_DT;
  const float* xp = ws + OFF_XP;
  const float* A2t = ws + OFF_A2;
  float* hend = ws + OFF_HEND;
  float* dtsum = ws + OFF_DTSUM;
  __shared__ float bs[CLEN * DD];
  int wg = blockIdx.x;
  int mw = wg & 3, c = (wg >> 2) & (NCH - 1), b = wg >> 8;
  int m = mw * 256 + threadIdx.x;
  int l0 = c * CLEN;
  for (int i = threadIdx.x; i < CLEN * DD; i += 256) {
    int r = i >> 4, cc = i & 15;
    bs[i] = xp[(size_t)(b * LL + l0 + r) * NN + RR + cc];
  }
  __syncthreads();
  float A2[DD], h[DD] = {};
#pragma unroll
  for (int k = 0; k < 4; ++k) {
    float4 v = *(const float4*)&A2t[m * DD + 4 * k];
    A2[4 * k] = v.x; A2[4 * k + 1] = v.y; A2[4 * k + 2] = v.z; A2[4 * k + 3] = v.w;
  }
  float S = 0.f;
  for (int lo = 0; lo < CLEN; ++lo) {
    size_t idx = ((size_t)(b * LL + l0 + lo)) * MM + m;
    float dtv = dt[idx];
    float xv = x[idx];
    S += dtv;
    float Bv[DD];
#pragma unroll
    for (int k = 0; k < 4; ++k) {
      float4 v = *(const float4*)&bs[lo * DD + 4 * k];
      Bv[4 * k] = v.x; Bv[4 * k + 1] = v.y; Bv[4 * k + 2] = v.z; Bv[4 * k + 3] = v.w;
    }
    float dtx = dtv * xv;
#pragma unroll
    for (int d = 0; d < DD; ++d)
      h[d] = exp2f(dtv * A2[d]) * h[d] + dtx * Bv[d];
  }
  size_t o = ((size_t)((c * BB + b) * MM + m)) * DD;
#pragma unroll
  for (int k = 0; k < 4; ++k)
    *(float4*)&hend[o + 4 * k] = make_float4(h[4 * k], h[4 * k + 1], h[4 * k + 2], h[4 * k + 3]);
  dtsum[(c * BB + b) * MM + m] = S;
}

// ---------------- scan phase 2: scan over chunks, h0 overwrites hend in place ----------------
__global__ __launch_bounds__(256) void k_scan2(float* __restrict__ ws) {
  int t = blockIdx.x * 256 + threadIdx.x; // 32768 threads
  int d = t & 15, m = (t >> 4) & 1023, b = t >> 14;
  float* hend = ws + OFF_HEND;
  const float* dtsum = ws + OFF_DTSUM;
  float A2 = ws[OFF_A2 + m * DD + d];
  float h = 0.f;
  for (int c = 0; c < NCH; ++c) {
    size_t o = ((size_t)((c * BB + b) * MM + m)) * DD + d;
    float he = hend[o];
    hend[o] = h;                         // h0 for chunk c
    float S = dtsum[(c * BB + b) * MM + m];
    h = exp2f(A2 * S) * h + he;
  }
}

// ---------------- scan phase 3: recompute with correct h0, emit y * silu(z) ----------------
__global__ __launch_bounds__(256) void k_scan3(const float* __restrict__ x,
                                               const float* __restrict__ z,
                                               const float* __restrict__ Dp,
                                               float* __restrict__ out,
                                               float* __restrict__ ws) {
  const float* dt = ws + OFF_DT;
  const float* xp = ws + OFF_XP;
  const float* A2t = ws + OFF_A2;
  const float* h0w = ws + OFF_HEND;      // phase 2 left h0 here
  __shared__ float bs[CLEN * 32];
  int wg = blockIdx.x;
  int mw = wg & 3, c = (wg >> 2) & (NCH - 1), b = wg >> 8;
  int m = mw * 256 + threadIdx.x;
  int l0 = c * CLEN;
  for (int i = threadIdx.x; i < CLEN * 32; i += 256) {
    int r = i >> 5, cc = i & 31;
    bs[i] = xp[(size_t)(b * LL + l0 + r) * NN + RR + cc];
  }
  __syncthreads();
  float A2[DD], h[DD];
#pragma unroll
  for (int k = 0; k < 4; ++k) {
    float4 v = *(const float4*)&A2t[m * DD + 4 * k];
    A2[4 * k] = v.x; A2[4 * k + 1] = v.y; A2[4 * k + 2] = v.z; A2[4 * k + 3] = v.w;
  }
  size_t o = ((size_t)((c * BB + b) * MM + m)) * DD;
#pragma unroll
  for (int k = 0; k < 4; ++k) {
    float4 v = *(const float4*)&h0w[o + 4 * k];
    h[4 * k] = v.x; h[4 * k + 1] = v.y; h[4 * k + 2] = v.z; h[4 * k + 3] = v.w;
  }
  float Dpm = Dp[m];
  for (int lo = 0; lo < CLEN; ++lo) {
    size_t idx = ((size_t)(b * LL + l0 + lo)) * MM + m;
    float dtv = dt[idx];
    float xv = x[idx];
    float zv = z[idx];
    float Bv[DD], Cv[DD];
#pragma unroll
    for (int k = 0; k < 4; ++k) {
      float4 v = *(const float4*)&bs[lo * 32 + 4 * k];
      Bv[4 * k] = v.x; Bv[4 * k + 1] = v.y; Bv[4 * k + 2] = v.z; Bv[4 * k + 3] = v.w;
      float4 u = *(const float4*)&bs[lo * 32 + DD + 4 * k];
      Cv[4 * k] = u.x; Cv[4 * k + 1] = u.y; Cv[4 * k + 2] = u.z; Cv[4 * k + 3] = u.w;
    }
    float dtx = dtv * xv;
    float y = 0.f;
#pragma unroll
    for (int d = 0; d < DD; ++d) {
      h[d] = exp2f(dtv * A2[d]) * h[d] + dtx * Bv[d];
      y += h[d] * Cv[d];
    }
    y += Dpm * xv;
    float sig = 1.f / (1.f + exp2f(-LOG2E * zv));
    out[idx] = y * zv * sig;
  }
}

extern "C" void kernel_launch(void* const* d_in, const int* in_sizes, int n_in,
                              void* d_out, int out_size, void* d_ws, size_t ws_size,
                              hipStream_t stream) {
  const float* x = (const float*)d_in[0];
  const float* z = (const float*)d_in[1];
  const float* W = (const float*)d_in[2];
  const float* dtW = (const float*)d_in[3];
  const float* dtb = (const float*)d_in[4];
  const float* A_log = (const float*)d_in[5];
  const float* Dp = (const float*)d_in[6];
  float* out = (float*)d_out;
  float* ws = (float*)d_ws;

  k_prep<<<704, 256, 0, stream>>>(W, dtW, A_log, ws);
  k_xp<<<256, 192, 0, stream>>>(x, ws);
  k_dt<<<1024, 256, 0, stream>>>(dtb, ws);
  k_scan1<<<4 * NCH * BB, 256, 0, stream>>>(x, ws);
  k_scan2<<<128, 256, 0, stream>>>(ws);
  k_scan3<<<4 * NCH * BB, 256, 0, stream>>>(x, z, Dp, out, ws);
}

// Round 3
// 177.766 us; speedup vs baseline: 1.2434x; 1.0361x over previous
//
#include <hip/hip_runtime.h>
#include <math.h>

#define BB 2
#define LL 2048
#define MM 1024
#define DD 16
#define RR 64
#define NN 96
#define BLROWS (BB*LL)          // 4096
#define NCH 64                  // chunks
#define CLEN (LL/NCH)           // 32

// workspace layout (float offsets)
#define OFF_XP    0
#define OFF_DT    (OFF_XP + BLROWS*NN)            // 393216
#define OFF_WT    (OFF_DT + BLROWS*MM)            // + 4194304
#define OFF_DTWT  (OFF_WT + MM*NN)                // + 98304
#define OFF_A2    (OFF_DTWT + RR*MM)              // + 65536
#define OFF_HEND  (OFF_A2 + MM*DD)                // + 16384
#define OFF_DTSUM (OFF_HEND + NCH*BB*MM*DD)       // + 2097152
// total = OFF_DTSUM + NCH*BB*MM = 6995968 floats = 28.0 MB

#define LOG2E 1.44269504088896340736f

__device__ __forceinline__ float softplusf(float v) {
  return v > 20.f ? v : log1pf(expf(v));
}

// ---------------- prep: transposes + A2 = -exp(A_log)^T * log2e ----------------
__global__ __launch_bounds__(256) void k_prep(const float* __restrict__ W,
                                              const float* __restrict__ dtW,
                                              const float* __restrict__ A_log,
                                              float* __restrict__ ws) {
  int idx = blockIdx.x * 256 + threadIdx.x;
  if (idx < MM * NN) {
    int m = idx / NN, n = idx % NN;
    ws[OFF_WT + idx] = W[n * MM + m];
  } else if (idx < MM * NN + RR * MM) {
    int j = idx - MM * NN;
    int r = j / MM, m = j % MM;
    ws[OFF_DTWT + j] = dtW[m * RR + r];
  } else if (idx < MM * NN + RR * MM + MM * DD) {
    int j = idx - MM * NN - RR * MM;
    int m = j / DD, d = j % DD;
    ws[OFF_A2 + j] = -expf(A_log[d * MM + m]) * LOG2E;
  }
}

// ---------------- xp = x @ W^T  (4096 x 96, K=1024) ----------------
// grid 512 wgs (8 rows each), block 192: nt=t%24 (4 n's), rt=t/24 (1 row).
// No LDS: x row read as broadcast float4 (24 lanes share the address),
// W streamed via L1/L2 (panel reused by every wg).
__global__ __launch_bounds__(192) void k_xp(const float* __restrict__ x,
                                            float* __restrict__ ws) {
  const float4* Wt4 = (const float4*)(ws + OFF_WT); // [m][24] float4
  float* xp = ws + OFF_XP;
  int nt = threadIdx.x % 24, rt = threadIdx.x / 24;
  int row = blockIdx.x * 8 + rt;
  const float4* xrow = (const float4*)(x + (size_t)row * MM);
  float ax = 0.f, ay = 0.f, az = 0.f, aw = 0.f;
#pragma unroll 2
  for (int m4 = 0; m4 < 256; ++m4) {
    float4 xv = xrow[m4];
    float xa[4] = {xv.x, xv.y, xv.z, xv.w};
#pragma unroll
    for (int j = 0; j < 4; ++j) {
      float4 w = Wt4[(m4 * 4 + j) * 24 + nt];
      ax += xa[j] * w.x; ay += xa[j] * w.y;
      az += xa[j] * w.z; aw += xa[j] * w.w;
    }
  }
  *(float4*)&xp[(size_t)row * NN + nt * 4] = make_float4(ax, ay, az, aw);
}

// ---------------- dt = softplus(xp[:, :64] @ dtW^T + b)  (4096 x 1024, K=64) ----------------
// grid (MM/256)*(BLROWS/16) = 4*256 = 1024 wgs, block 256.
// tid: mt = t&63 (4 m's as one float4), rg = t>>6 (4 rows). acc[4][4] = 16 regs, no spill.
__global__ __launch_bounds__(256) void k_dt(const float* __restrict__ dtb,
                                            float* __restrict__ ws) {
  const float* xp = ws + OFF_XP;
  const float4* dtWt4 = (const float4*)(ws + OFF_DTWT); // [r][256] float4
  float* dt = ws + OFF_DT;
  __shared__ float xs[16 * 64];
  int mb = blockIdx.x & 3;
  int bl0 = (blockIdx.x >> 2) * 16;
  int t = threadIdx.x;
  {
    int r = t >> 4, c4 = t & 15;
    *(float4*)&xs[r * 64 + c4 * 4] = *(const float4*)&xp[(size_t)(bl0 + r) * NN + c4 * 4];
  }
  __syncthreads();
  int mt = t & 63, rg = t >> 6;
  int m4 = mb * 64 + mt;   // float4 index into m (0..255)
  float acc[4][4] = {};
  for (int k4 = 0; k4 < 16; ++k4) {
    float4 w0 = dtWt4[(k4 * 4 + 0) * 256 + m4];
    float4 w1 = dtWt4[(k4 * 4 + 1) * 256 + m4];
    float4 w2 = dtWt4[(k4 * 4 + 2) * 256 + m4];
    float4 w3 = dtWt4[(k4 * 4 + 3) * 256 + m4];
#pragma unroll
    for (int r = 0; r < 4; ++r) {
      float4 xv = *(const float4*)&xs[(rg * 4 + r) * 64 + k4 * 4];
      acc[r][0] += xv.x * w0.x + xv.y * w1.x + xv.z * w2.x + xv.w * w3.x;
      acc[r][1] += xv.x * w0.y + xv.y * w1.y + xv.z * w2.y + xv.w * w3.y;
      acc[r][2] += xv.x * w0.z + xv.y * w1.z + xv.z * w2.z + xv.w * w3.z;
      acc[r][3] += xv.x * w0.w + xv.y * w1.w + xv.z * w2.w + xv.w * w3.w;
    }
  }
  float4 bv = *(const float4*)&dtb[m4 * 4];
#pragma unroll
  for (int r = 0; r < 4; ++r) {
    float4 o;
    o.x = softplusf(acc[r][0] + bv.x);
    o.y = softplusf(acc[r][1] + bv.y);
    o.z = softplusf(acc[r][2] + bv.z);
    o.w = softplusf(acc[r][3] + bv.w);
    *(float4*)&dt[(size_t)(bl0 + rg * 4 + r) * MM + m4 * 4] = o;
  }
}

// ---------------- scan phase 1: per-chunk h_end and sum(dt) ----------------
// grid 4*NCH*BB = 512 wgs, block 256 (thread = m within quarter)
__global__ __launch_bounds__(256) void k_scan1(const float* __restrict__ x,
                                               float* __restrict__ ws) {
  const float* dt = ws + OFF_DT;
  const float* xp = ws + OFF_XP;
  const float* A2t = ws + OFF_A2;
  float* hend = ws + OFF_HEND;
  float* dtsum = ws + OFF_DTSUM;
  __shared__ float bs[CLEN * DD];
  int wg = blockIdx.x;
  int mw = wg & 3, c = (wg >> 2) & (NCH - 1), b = wg >> 8;
  int m = mw * 256 + threadIdx.x;
  int l0 = c * CLEN;
  for (int i = threadIdx.x; i < CLEN * DD; i += 256) {
    int r = i >> 4, cc = i & 15;
    bs[i] = xp[(size_t)(b * LL + l0 + r) * NN + RR + cc];
  }
  __syncthreads();
  float A2[DD], h[DD] = {};
#pragma unroll
  for (int k = 0; k < 4; ++k) {
    float4 v = *(const float4*)&A2t[m * DD + 4 * k];
    A2[4 * k] = v.x; A2[4 * k + 1] = v.y; A2[4 * k + 2] = v.z; A2[4 * k + 3] = v.w;
  }
  float S = 0.f;
  for (int lo = 0; lo < CLEN; ++lo) {
    size_t idx = ((size_t)(b * LL + l0 + lo)) * MM + m;
    float dtv = dt[idx];
    float xv = x[idx];
    S += dtv;
    float Bv[DD];
#pragma unroll
    for (int k = 0; k < 4; ++k) {
      float4 v = *(const float4*)&bs[lo * DD + 4 * k];
      Bv[4 * k] = v.x; Bv[4 * k + 1] = v.y; Bv[4 * k + 2] = v.z; Bv[4 * k + 3] = v.w;
    }
    float dtx = dtv * xv;
#pragma unroll
    for (int d = 0; d < DD; ++d)
      h[d] = exp2f(dtv * A2[d]) * h[d] + dtx * Bv[d];
  }
  size_t o = ((size_t)((c * BB + b) * MM + m)) * DD;
#pragma unroll
  for (int k = 0; k < 4; ++k)
    *(float4*)&hend[o + 4 * k] = make_float4(h[4 * k], h[4 * k + 1], h[4 * k + 2], h[4 * k + 3]);
  dtsum[(c * BB + b) * MM + m] = S;
}

// ---------------- scan phase 2: scan over chunks, h0 overwrites hend in place ----------------
__global__ __launch_bounds__(256) void k_scan2(float* __restrict__ ws) {
  int t = blockIdx.x * 256 + threadIdx.x; // 32768 threads
  int d = t & 15, m = (t >> 4) & 1023, b = t >> 14;
  float* hend = ws + OFF_HEND;
  const float* dtsum = ws + OFF_DTSUM;
  float A2 = ws[OFF_A2 + m * DD + d];
  float h = 0.f;
  for (int c = 0; c < NCH; ++c) {
    size_t o = ((size_t)((c * BB + b) * MM + m)) * DD + d;
    float he = hend[o];
    hend[o] = h;                         // h0 for chunk c
    float S = dtsum[(c * BB + b) * MM + m];
    h = exp2f(A2 * S) * h + he;
  }
}

// ---------------- scan phase 3: recompute with correct h0, emit y * silu(z) ----------------
__global__ __launch_bounds__(256) void k_scan3(const float* __restrict__ x,
                                               const float* __restrict__ z,
                                               const float* __restrict__ Dp,
                                               float* __restrict__ out,
                                               float* __restrict__ ws) {
  const float* dt = ws + OFF_DT;
  const float* xp = ws + OFF_XP;
  const float* A2t = ws + OFF_A2;
  const float* h0w = ws + OFF_HEND;      // phase 2 left h0 here
  __shared__ float bs[CLEN * 32];
  int wg = blockIdx.x;
  int mw = wg & 3, c = (wg >> 2) & (NCH - 1), b = wg >> 8;
  int m = mw * 256 + threadIdx.x;
  int l0 = c * CLEN;
  for (int i = threadIdx.x; i < CLEN * 32; i += 256) {
    int r = i >> 5, cc = i & 31;
    bs[i] = xp[(size_t)(b * LL + l0 + r) * NN + RR + cc];
  }
  __syncthreads();
  float A2[DD], h[DD];
#pragma unroll
  for (int k = 0; k < 4; ++k) {
    float4 v = *(const float4*)&A2t[m * DD + 4 * k];
    A2[4 * k] = v.x; A2[4 * k + 1] = v.y; A2[4 * k + 2] = v.z; A2[4 * k + 3] = v.w;
  }
  size_t o = ((size_t)((c * BB + b) * MM + m)) * DD;
#pragma unroll
  for (int k = 0; k < 4; ++k) {
    float4 v = *(const float4*)&h0w[o + 4 * k];
    h[4 * k] = v.x; h[4 * k + 1] = v.y; h[4 * k + 2] = v.z; h[4 * k + 3] = v.w;
  }
  float Dpm = Dp[m];
  for (int lo = 0; lo < CLEN; ++lo) {
    size_t idx = ((size_t)(b * LL + l0 + lo)) * MM + m;
    float dtv = dt[idx];
    float xv = x[idx];
    float zv = z[idx];
    float Bv[DD], Cv[DD];
#pragma unroll
    for (int k = 0; k < 4; ++k) {
      float4 v = *(const float4*)&bs[lo * 32 + 4 * k];
      Bv[4 * k] = v.x; Bv[4 * k + 1] = v.y; Bv[4 * k + 2] = v.z; Bv[4 * k + 3] = v.w;
      float4 u = *(const float4*)&bs[lo * 32 + DD + 4 * k];
      Cv[4 * k] = u.x; Cv[4 * k + 1] = u.y; Cv[4 * k + 2] = u.z; Cv[4 * k + 3] = u.w;
    }
    float dtx = dtv * xv;
    float y = 0.f;
#pragma unroll
    for (int d = 0; d < DD; ++d) {
      h[d] = exp2f(dtv * A2[d]) * h[d] + dtx * Bv[d];
      y += h[d] * Cv[d];
    }
    y += Dpm * xv;
    float sig = 1.f / (1.f + exp2f(-LOG2E * zv));
    out[idx] = y * zv * sig;
  }
}

extern "C" void kernel_launch(void* const* d_in, const int* in_sizes, int n_in,
                              void* d_out, int out_size, void* d_ws, size_t ws_size,
                              hipStream_t stream) {
  const float* x = (const float*)d_in[0];
  const float* z = (const float*)d_in[1];
  const float* W = (const float*)d_in[2];
  const float* dtW = (const float*)d_in[3];
  const float* dtb = (const float*)d_in[4];
  const float* A_log = (const float*)d_in[5];
  const float* Dp = (const float*)d_in[6];
  float* out = (float*)d_out;
  float* ws = (float*)d_ws;

  k_prep<<<704, 256, 0, stream>>>(W, dtW, A_log, ws);
  k_xp<<<512, 192, 0, stream>>>(x, ws);
  k_dt<<<1024, 256, 0, stream>>>(dtb, ws);
  k_scan1<<<4 * NCH * BB, 256, 0, stream>>>(x, ws);
  k_scan2<<<128, 256, 0, stream>>>(ws);
  k_scan3<<<4 * NCH * BB, 256, 0, stream>>>(x, z, Dp, out, ws);
}

// Round 4
// 142.140 us; speedup vs baseline: 1.5550x; 1.2506x over previous
//
#include <hip/hip_runtime.h>
#include <math.h>

#define BB 2
#define LL 2048
#define MM 1024
#define DD 16
#define RR 64
#define NN 96
#define BLROWS (BB*LL)          // 4096
#define NCH 64                  // chunks
#define CLEN (LL/NCH)           // 32

// workspace layout (float offsets)
#define OFF_XP    0
#define OFF_DT    (OFF_XP + BLROWS*NN)            // 393216
#define OFF_WT    (OFF_DT + BLROWS*MM)            // + 4194304 (unused now)
#define OFF_DTWT  (OFF_WT + MM*NN)                // + 98304
#define OFF_A2    (OFF_DTWT + RR*MM)              // + 65536
#define OFF_HEND  (OFF_A2 + MM*DD)                // + 16384
#define OFF_DTSUM (OFF_HEND + NCH*BB*MM*DD)       // + 2097152
// total = OFF_DTSUM + NCH*BB*MM = 6995968 floats = 28.0 MB

#define LOG2E 1.44269504088896340736f

typedef __attribute__((ext_vector_type(8))) short bf16x8;
typedef __attribute__((ext_vector_type(4))) float f32x4;

__device__ __forceinline__ float softplusf(float v) {
  return v > 20.f ? v : log1pf(expf(v));
}

// f32 -> bf16 round-to-nearest-even
__device__ __forceinline__ short f2bf(float f) {
  union { float f; unsigned u; } v; v.f = f;
  unsigned r = v.u + 0x7FFFu + ((v.u >> 16) & 1u);
  return (short)(r >> 16);
}

// ---------------- prep: dtW transpose + A2 = -exp(A_log)^T * log2e ----------------
__global__ __launch_bounds__(256) void k_prep(const float* __restrict__ dtW,
                                              const float* __restrict__ A_log,
                                              float* __restrict__ ws) {
  int idx = blockIdx.x * 256 + threadIdx.x;
  if (idx < RR * MM) {
    int r = idx / MM, m = idx % MM;
    ws[OFF_DTWT + idx] = dtW[m * RR + r];
  } else if (idx < RR * MM + MM * DD) {
    int j = idx - RR * MM;
    int m = j / DD, d = j % DD;
    ws[OFF_A2 + j] = -expf(A_log[d * MM + m]) * LOG2E;
  }
}

// ---------------- xp = x @ W^T  (4096 x 96, K=1024) via bf16 MFMA ----------------
// One wave per 16x16 output tile. TN layout: x[row][k], W[n][k] both K-contiguous
// = native mfma_f32_16x16x32_bf16 fragment layout. f32 loads, RNE->bf16, f32 acc.
__global__ __launch_bounds__(64) void k_xp(const float* __restrict__ x,
                                           const float* __restrict__ W,
                                           float* __restrict__ ws) {
  float* xp = ws + OFF_XP;
  int lane = threadIdx.x;
  int rt = blockIdx.x / 6, nt = blockIdx.x % 6;
  int lr = lane & 15, lk = lane >> 4;
  const float* xr = x + (size_t)(rt * 16 + lr) * MM + lk * 8;
  const float* wr = W + (size_t)(nt * 16 + lr) * MM + lk * 8;
  f32x4 acc = {0.f, 0.f, 0.f, 0.f};
#pragma unroll 4
  for (int kk = 0; kk < MM; kk += 32) {
    float4 xa = *(const float4*)(xr + kk);
    float4 xb = *(const float4*)(xr + kk + 4);
    float4 wa = *(const float4*)(wr + kk);
    float4 wb = *(const float4*)(wr + kk + 4);
    bf16x8 a, b;
    a[0] = f2bf(xa.x); a[1] = f2bf(xa.y); a[2] = f2bf(xa.z); a[3] = f2bf(xa.w);
    a[4] = f2bf(xb.x); a[5] = f2bf(xb.y); a[6] = f2bf(xb.z); a[7] = f2bf(xb.w);
    b[0] = f2bf(wa.x); b[1] = f2bf(wa.y); b[2] = f2bf(wa.z); b[3] = f2bf(wa.w);
    b[4] = f2bf(wb.x); b[5] = f2bf(wb.y); b[6] = f2bf(wb.z); b[7] = f2bf(wb.w);
    acc = __builtin_amdgcn_mfma_f32_16x16x32_bf16(a, b, acc, 0, 0, 0);
  }
  // D layout: col = lane&15, row = (lane>>4)*4 + e
  int r0 = rt * 16 + lk * 4, c = nt * 16 + lr;
#pragma unroll
  for (int e = 0; e < 4; ++e)
    xp[(size_t)(r0 + e) * NN + c] = acc[e];
}

// ---------------- dt = softplus(xp[:, :64] @ dtW^T + b)  (4096 x 1024, K=64) ----------------
__global__ __launch_bounds__(256) void k_dt(const float* __restrict__ dtb,
                                            float* __restrict__ ws) {
  const float* xp = ws + OFF_XP;
  const float4* dtWt4 = (const float4*)(ws + OFF_DTWT); // [r][256] float4
  float* dt = ws + OFF_DT;
  __shared__ float xs[16 * 64];
  int mb = blockIdx.x & 3;
  int bl0 = (blockIdx.x >> 2) * 16;
  int t = threadIdx.x;
  {
    int r = t >> 4, c4 = t & 15;
    *(float4*)&xs[r * 64 + c4 * 4] = *(const float4*)&xp[(size_t)(bl0 + r) * NN + c4 * 4];
  }
  __syncthreads();
  int mt = t & 63, rg = t >> 6;
  int m4 = mb * 64 + mt;   // float4 index into m (0..255)
  float acc[4][4] = {};
  for (int k4 = 0; k4 < 16; ++k4) {
    float4 w0 = dtWt4[(k4 * 4 + 0) * 256 + m4];
    float4 w1 = dtWt4[(k4 * 4 + 1) * 256 + m4];
    float4 w2 = dtWt4[(k4 * 4 + 2) * 256 + m4];
    float4 w3 = dtWt4[(k4 * 4 + 3) * 256 + m4];
#pragma unroll
    for (int r = 0; r < 4; ++r) {
      float4 xv = *(const float4*)&xs[(rg * 4 + r) * 64 + k4 * 4];
      acc[r][0] += xv.x * w0.x + xv.y * w1.x + xv.z * w2.x + xv.w * w3.x;
      acc[r][1] += xv.x * w0.y + xv.y * w1.y + xv.z * w2.y + xv.w * w3.y;
      acc[r][2] += xv.x * w0.z + xv.y * w1.z + xv.z * w2.z + xv.w * w3.z;
      acc[r][3] += xv.x * w0.w + xv.y * w1.w + xv.z * w2.w + xv.w * w3.w;
    }
  }
  float4 bv = *(const float4*)&dtb[m4 * 4];
#pragma unroll
  for (int r = 0; r < 4; ++r) {
    float4 o;
    o.x = softplusf(acc[r][0] + bv.x);
    o.y = softplusf(acc[r][1] + bv.y);
    o.z = softplusf(acc[r][2] + bv.z);
    o.w = softplusf(acc[r][3] + bv.w);
    *(float4*)&dt[(size_t)(bl0 + rg * 4 + r) * MM + m4 * 4] = o;
  }
}

// ---------------- scan phase 1: per-chunk h_end and sum(dt) ----------------
__global__ __launch_bounds__(256) void k_scan1(const float* __restrict__ x,
                                               float* __restrict__ ws) {
  const float* dt = ws + OFF_DT;
  const float* xp = ws + OFF_XP;
  const float* A2t = ws + OFF_A2;
  float* hend = ws + OFF_HEND;
  float* dtsum = ws + OFF_DTSUM;
  __shared__ float bs[CLEN * DD];
  int wg = blockIdx.x;
  int mw = wg & 3, c = (wg >> 2) & (NCH - 1), b = wg >> 8;
  int m = mw * 256 + threadIdx.x;
  int l0 = c * CLEN;
  for (int i = threadIdx.x; i < CLEN * DD; i += 256) {
    int r = i >> 4, cc = i & 15;
    bs[i] = xp[(size_t)(b * LL + l0 + r) * NN + RR + cc];
  }
  __syncthreads();
  float A2[DD], h[DD] = {};
#pragma unroll
  for (int k = 0; k < 4; ++k) {
    float4 v = *(const float4*)&A2t[m * DD + 4 * k];
    A2[4 * k] = v.x; A2[4 * k + 1] = v.y; A2[4 * k + 2] = v.z; A2[4 * k + 3] = v.w;
  }
  float S = 0.f;
  for (int lo = 0; lo < CLEN; ++lo) {
    size_t idx = ((size_t)(b * LL + l0 + lo)) * MM + m;
    float dtv = dt[idx];
    float xv = x[idx];
    S += dtv;
    float Bv[DD];
#pragma unroll
    for (int k = 0; k < 4; ++k) {
      float4 v = *(const float4*)&bs[lo * DD + 4 * k];
      Bv[4 * k] = v.x; Bv[4 * k + 1] = v.y; Bv[4 * k + 2] = v.z; Bv[4 * k + 3] = v.w;
    }
    float dtx = dtv * xv;
#pragma unroll
    for (int d = 0; d < DD; ++d)
      h[d] = exp2f(dtv * A2[d]) * h[d] + dtx * Bv[d];
  }
  size_t o = ((size_t)((c * BB + b) * MM + m)) * DD;
#pragma unroll
  for (int k = 0; k < 4; ++k)
    *(float4*)&hend[o + 4 * k] = make_float4(h[4 * k], h[4 * k + 1], h[4 * k + 2], h[4 * k + 3]);
  dtsum[(c * BB + b) * MM + m] = S;
}

// ---------------- scan phase 2: scan over chunks (software-pipelined), h0 in place ----------------
__global__ __launch_bounds__(256) void k_scan2(float* __restrict__ ws) {
  int t = blockIdx.x * 256 + threadIdx.x; // 32768 threads
  int d = t & 15, m = (t >> 4) & 1023, b = t >> 14;
  float* hend = ws + OFF_HEND;
  const float* dtsum = ws + OFF_DTSUM;
  float A2 = ws[OFF_A2 + m * DD + d];
  const size_t hstride = (size_t)BB * MM * DD;
  const int sstride = BB * MM;
  size_t o = ((size_t)b * MM + m) * DD + d;
  int si = b * MM + m;
  float h = 0.f;
  float he = hend[o], S = dtsum[si];
  for (int c = 0; c < NCH; ++c) {
    float heN = 0.f, SN = 0.f;
    if (c + 1 < NCH) {            // prefetch next chunk BEFORE this chunk's store
      heN = hend[o + hstride];
      SN = dtsum[si + sstride];
    }
    hend[o] = h;                  // h0 for chunk c
    h = exp2f(A2 * S) * h + he;
    he = heN; S = SN;
    o += hstride; si += sstride;
  }
}

// ---------------- scan phase 3: recompute with correct h0, emit y * silu(z) ----------------
__global__ __launch_bounds__(256) void k_scan3(const float* __restrict__ x,
                                               const float* __restrict__ z,
                                               const float* __restrict__ Dp,
                                               float* __restrict__ out,
                                               float* __restrict__ ws) {
  const float* dt = ws + OFF_DT;
  const float* xp = ws + OFF_XP;
  const float* A2t = ws + OFF_A2;
  const float* h0w = ws + OFF_HEND;      // phase 2 left h0 here
  __shared__ float bs[CLEN * 32];
  int wg = blockIdx.x;
  int mw = wg & 3, c = (wg >> 2) & (NCH - 1), b = wg >> 8;
  int m = mw * 256 + threadIdx.x;
  int l0 = c * CLEN;
  for (int i = threadIdx.x; i < CLEN * 32; i += 256) {
    int r = i >> 5, cc = i & 31;
    bs[i] = xp[(size_t)(b * LL + l0 + r) * NN + RR + cc];
  }
  __syncthreads();
  float A2[DD], h[DD];
#pragma unroll
  for (int k = 0; k < 4; ++k) {
    float4 v = *(const float4*)&A2t[m * DD + 4 * k];
    A2[4 * k] = v.x; A2[4 * k + 1] = v.y; A2[4 * k + 2] = v.z; A2[4 * k + 3] = v.w;
  }
  size_t o = ((size_t)((c * BB + b) * MM + m)) * DD;
#pragma unroll
  for (int k = 0; k < 4; ++k) {
    float4 v = *(const float4*)&h0w[o + 4 * k];
    h[4 * k] = v.x; h[4 * k + 1] = v.y; h[4 * k + 2] = v.z; h[4 * k + 3] = v.w;
  }
  float Dpm = Dp[m];
  for (int lo = 0; lo < CLEN; ++lo) {
    size_t idx = ((size_t)(b * LL + l0 + lo)) * MM + m;
    float dtv = dt[idx];
    float xv = x[idx];
    float zv = z[idx];
    float Bv[DD], Cv[DD];
#pragma unroll
    for (int k = 0; k < 4; ++k) {
      float4 v = *(const float4*)&bs[lo * 32 + 4 * k];
      Bv[4 * k] = v.x; Bv[4 * k + 1] = v.y; Bv[4 * k + 2] = v.z; Bv[4 * k + 3] = v.w;
      float4 u = *(const float4*)&bs[lo * 32 + DD + 4 * k];
      Cv[4 * k] = u.x; Cv[4 * k + 1] = u.y; Cv[4 * k + 2] = u.z; Cv[4 * k + 3] = u.w;
    }
    float dtx = dtv * xv;
    float y = 0.f;
#pragma unroll
    for (int d = 0; d < DD; ++d) {
      h[d] = exp2f(dtv * A2[d]) * h[d] + dtx * Bv[d];
      y += h[d] * Cv[d];
    }
    y += Dpm * xv;
    float sig = 1.f / (1.f + exp2f(-LOG2E * zv));
    out[idx] = y * zv * sig;
  }
}

extern "C" void kernel_launch(void* const* d_in, const int* in_sizes, int n_in,
                              void* d_out, int out_size, void* d_ws, size_t ws_size,
                              hipStream_t stream) {
  const float* x = (const float*)d_in[0];
  const float* z = (const float*)d_in[1];
  const float* W = (const float*)d_in[2];
  const float* dtW = (const float*)d_in[3];
  const float* dtb = (const float*)d_in[4];
  const float* A_log = (const float*)d_in[5];
  const float* Dp = (const float*)d_in[6];
  float* out = (float*)d_out;
  float* ws = (float*)d_ws;

  k_prep<<<320, 256, 0, stream>>>(dtW, A_log, ws);
  k_xp<<<(BLROWS / 16) * 6, 64, 0, stream>>>(x, W, ws);
  k_dt<<<1024, 256, 0, stream>>>(dtb, ws);
  k_scan1<<<4 * NCH * BB, 256, 0, stream>>>(x, ws);
  k_scan2<<<128, 256, 0, stream>>>(ws);
  k_scan3<<<4 * NCH * BB, 256, 0, stream>>>(x, z, Dp, out, ws);
}

// Round 5
// 133.818 us; speedup vs baseline: 1.6517x; 1.0622x over previous
//
#include <hip/hip_runtime.h>
#include <math.h>

#define BB 2
#define LL 2048
#define MM 1024
#define DD 16
#define RR 64
#define NN 96
#define BLROWS (BB*LL)          // 4096
#define NCH 64                  // chunks
#define CLEN (LL/NCH)           // 32

// workspace layout (float offsets)
#define OFF_XP    0
#define OFF_DT    (OFF_XP + BLROWS*NN)            // 393216
#define OFF_WT    (OFF_DT + BLROWS*MM)            // + 4194304 (unused now)
#define OFF_DTWT  (OFF_WT + MM*NN)                // + 98304
#define OFF_A2    (OFF_DTWT + RR*MM)              // + 65536
#define OFF_HEND  (OFF_A2 + MM*DD)                // + 16384
#define OFF_DTSUM (OFF_HEND + NCH*BB*MM*DD)       // + 2097152
// total = OFF_DTSUM + NCH*BB*MM = 6995968 floats = 28.0 MB

#define LOG2E 1.44269504088896340736f

typedef __attribute__((ext_vector_type(8))) short bf16x8;
typedef __attribute__((ext_vector_type(4))) float f32x4;

__device__ __forceinline__ float softplusf(float v) {
  return v > 20.f ? v : log1pf(expf(v));
}

// f32 -> bf16 round-to-nearest-even
__device__ __forceinline__ short f2bf(float f) {
  union { float f; unsigned u; } v; v.f = f;
  unsigned r = v.u + 0x7FFFu + ((v.u >> 16) & 1u);
  return (short)(r >> 16);
}

// ---------------- prep: dtW transpose + A2 = -exp(A_log)^T * log2e ----------------
__global__ __launch_bounds__(256) void k_prep(const float* __restrict__ dtW,
                                              const float* __restrict__ A_log,
                                              float* __restrict__ ws) {
  int idx = blockIdx.x * 256 + threadIdx.x;
  if (idx < RR * MM) {
    int r = idx / MM, m = idx % MM;
    ws[OFF_DTWT + idx] = dtW[m * RR + r];
  } else if (idx < RR * MM + MM * DD) {
    int j = idx - RR * MM;
    int m = j / DD, d = j % DD;
    ws[OFF_A2 + j] = -expf(A_log[d * MM + m]) * LOG2E;
  }
}

// ---------------- xp = x @ W^T  (4096 x 96, K=1024) via bf16 MFMA ----------------
__global__ __launch_bounds__(64) void k_xp(const float* __restrict__ x,
                                           const float* __restrict__ W,
                                           float* __restrict__ ws) {
  float* xp = ws + OFF_XP;
  int lane = threadIdx.x;
  int rt = blockIdx.x / 6, nt = blockIdx.x % 6;
  int lr = lane & 15, lk = lane >> 4;
  const float* xr = x + (size_t)(rt * 16 + lr) * MM + lk * 8;
  const float* wr = W + (size_t)(nt * 16 + lr) * MM + lk * 8;
  f32x4 acc = {0.f, 0.f, 0.f, 0.f};
#pragma unroll 4
  for (int kk = 0; kk < MM; kk += 32) {
    float4 xa = *(const float4*)(xr + kk);
    float4 xb = *(const float4*)(xr + kk + 4);
    float4 wa = *(const float4*)(wr + kk);
    float4 wb = *(const float4*)(wr + kk + 4);
    bf16x8 a, b;
    a[0] = f2bf(xa.x); a[1] = f2bf(xa.y); a[2] = f2bf(xa.z); a[3] = f2bf(xa.w);
    a[4] = f2bf(xb.x); a[5] = f2bf(xb.y); a[6] = f2bf(xb.z); a[7] = f2bf(xb.w);
    b[0] = f2bf(wa.x); b[1] = f2bf(wa.y); b[2] = f2bf(wa.z); b[3] = f2bf(wa.w);
    b[4] = f2bf(wb.x); b[5] = f2bf(wb.y); b[6] = f2bf(wb.z); b[7] = f2bf(wb.w);
    acc = __builtin_amdgcn_mfma_f32_16x16x32_bf16(a, b, acc, 0, 0, 0);
  }
  int r0 = rt * 16 + lk * 4, c = nt * 16 + lr;
#pragma unroll
  for (int e = 0; e < 4; ++e)
    xp[(size_t)(r0 + e) * NN + c] = acc[e];
}

// ---------------- dt = softplus(xp[:, :64] @ dtW^T + b)  (4096 x 1024, K=64) ----------------
__global__ __launch_bounds__(256) void k_dt(const float* __restrict__ dtb,
                                            float* __restrict__ ws) {
  const float* xp = ws + OFF_XP;
  const float4* dtWt4 = (const float4*)(ws + OFF_DTWT); // [r][256] float4
  float* dt = ws + OFF_DT;
  __shared__ float xs[16 * 64];
  int mb = blockIdx.x & 3;
  int bl0 = (blockIdx.x >> 2) * 16;
  int t = threadIdx.x;
  {
    int r = t >> 4, c4 = t & 15;
    *(float4*)&xs[r * 64 + c4 * 4] = *(const float4*)&xp[(size_t)(bl0 + r) * NN + c4 * 4];
  }
  __syncthreads();
  int mt = t & 63, rg = t >> 6;
  int m4 = mb * 64 + mt;   // float4 index into m (0..255)
  float acc[4][4] = {};
  for (int k4 = 0; k4 < 16; ++k4) {
    float4 w0 = dtWt4[(k4 * 4 + 0) * 256 + m4];
    float4 w1 = dtWt4[(k4 * 4 + 1) * 256 + m4];
    float4 w2 = dtWt4[(k4 * 4 + 2) * 256 + m4];
    float4 w3 = dtWt4[(k4 * 4 + 3) * 256 + m4];
#pragma unroll
    for (int r = 0; r < 4; ++r) {
      float4 xv = *(const float4*)&xs[(rg * 4 + r) * 64 + k4 * 4];
      acc[r][0] += xv.x * w0.x + xv.y * w1.x + xv.z * w2.x + xv.w * w3.x;
      acc[r][1] += xv.x * w0.y + xv.y * w1.y + xv.z * w2.y + xv.w * w3.y;
      acc[r][2] += xv.x * w0.z + xv.y * w1.z + xv.z * w2.z + xv.w * w3.z;
      acc[r][3] += xv.x * w0.w + xv.y * w1.w + xv.z * w2.w + xv.w * w3.w;
    }
  }
  float4 bv = *(const float4*)&dtb[m4 * 4];
#pragma unroll
  for (int r = 0; r < 4; ++r) {
    float4 o;
    o.x = softplusf(acc[r][0] + bv.x);
    o.y = softplusf(acc[r][1] + bv.y);
    o.z = softplusf(acc[r][2] + bv.z);
    o.w = softplusf(acc[r][3] + bv.w);
    *(float4*)&dt[(size_t)(bl0 + rg * 4 + r) * MM + m4 * 4] = o;
  }
}

// ---------------- scan phase 1: per-chunk h_end and sum(dt) ----------------
// d-split: thread = (m, d-quartet). grid (MM/64)*NCH*BB = 2048 wgs, block 256.
__global__ __launch_bounds__(256) void k_scan1(const float* __restrict__ x,
                                               float* __restrict__ ws) {
  const float* dt = ws + OFF_DT;
  const float* xp = ws + OFF_XP;
  const float* A2t = ws + OFF_A2;
  float* hend = ws + OFF_HEND;
  float* dtsum = ws + OFF_DTSUM;
  __shared__ float bs[CLEN * DD];
  int wg = blockIdx.x;
  int mw = wg & 15, c = (wg >> 4) & (NCH - 1), b = wg >> 10;
  int t = threadIdx.x;
  int ml = t >> 2, dsub = t & 3;
  int m = mw * 64 + ml;
  int l0 = c * CLEN;
  for (int i = t; i < CLEN * DD; i += 256) {
    int r = i >> 4, cc = i & 15;
    bs[i] = xp[(size_t)(b * LL + l0 + r) * NN + RR + cc];
  }
  __syncthreads();
  float4 A2v = *(const float4*)&A2t[m * DD + dsub * 4];
  float h0_ = 0.f, h1_ = 0.f, h2_ = 0.f, h3_ = 0.f;
  float S = 0.f;
  size_t idx = ((size_t)(b * LL + l0)) * MM + m;
  float dtv = dt[idx], xv = x[idx];
#pragma unroll 2
  for (int lo = 0; lo < CLEN; ++lo) {
    float dtN = 0.f, xN = 0.f;
    if (lo + 1 < CLEN) {           // prefetch next timestep ahead of exp chain
      dtN = dt[idx + MM]; xN = x[idx + MM];
    }
    S += dtv;
    float4 Bv = *(const float4*)&bs[lo * DD + dsub * 4];
    float dtx = dtv * xv;
    h0_ = exp2f(dtv * A2v.x) * h0_ + dtx * Bv.x;
    h1_ = exp2f(dtv * A2v.y) * h1_ + dtx * Bv.y;
    h2_ = exp2f(dtv * A2v.z) * h2_ + dtx * Bv.z;
    h3_ = exp2f(dtv * A2v.w) * h3_ + dtx * Bv.w;
    dtv = dtN; xv = xN; idx += MM;
  }
  size_t o = ((size_t)((c * BB + b) * MM + m)) * DD + dsub * 4;
  *(float4*)&hend[o] = make_float4(h0_, h1_, h2_, h3_);
  if (dsub == 0) dtsum[(c * BB + b) * MM + m] = S;
}

// ---------------- scan phase 2: scan over chunks (software-pipelined), h0 in place ----------------
__global__ __launch_bounds__(256) void k_scan2(float* __restrict__ ws) {
  int t = blockIdx.x * 256 + threadIdx.x; // 32768 threads
  int d = t & 15, m = (t >> 4) & 1023, b = t >> 14;
  float* hend = ws + OFF_HEND;
  const float* dtsum = ws + OFF_DTSUM;
  float A2 = ws[OFF_A2 + m * DD + d];
  const size_t hstride = (size_t)BB * MM * DD;
  const int sstride = BB * MM;
  size_t o = ((size_t)b * MM + m) * DD + d;
  int si = b * MM + m;
  float h = 0.f;
  float he = hend[o], S = dtsum[si];
  for (int c = 0; c < NCH; ++c) {
    float heN = 0.f, SN = 0.f;
    if (c + 1 < NCH) {
      heN = hend[o + hstride];
      SN = dtsum[si + sstride];
    }
    hend[o] = h;                  // h0 for chunk c
    h = exp2f(A2 * S) * h + he;
    he = heN; S = SN;
    o += hstride; si += sstride;
  }
}

// ---------------- scan phase 3: recompute with h0, emit y * silu(z). d-split x4 ----------------
__global__ __launch_bounds__(256) void k_scan3(const float* __restrict__ x,
                                               const float* __restrict__ z,
                                               const float* __restrict__ Dp,
                                               float* __restrict__ out,
                                               float* __restrict__ ws) {
  const float* dt = ws + OFF_DT;
  const float* xp = ws + OFF_XP;
  const float* A2t = ws + OFF_A2;
  const float* h0w = ws + OFF_HEND;      // phase 2 left h0 here
  __shared__ float bs[CLEN * 32];
  int wg = blockIdx.x;
  int mw = wg & 15, c = (wg >> 4) & (NCH - 1), b = wg >> 10;
  int t = threadIdx.x;
  int ml = t >> 2, dsub = t & 3;
  int m = mw * 64 + ml;
  int l0 = c * CLEN;
  for (int i = t; i < CLEN * 32; i += 256) {
    int r = i >> 5, cc = i & 31;
    bs[i] = xp[(size_t)(b * LL + l0 + r) * NN + RR + cc];
  }
  __syncthreads();
  float4 A2v = *(const float4*)&A2t[m * DD + dsub * 4];
  size_t o = ((size_t)((c * BB + b) * MM + m)) * DD + dsub * 4;
  float4 hv = *(const float4*)&h0w[o];
  float h0_ = hv.x, h1_ = hv.y, h2_ = hv.z, h3_ = hv.w;
  float Dpm = Dp[m];
  size_t idx = ((size_t)(b * LL + l0)) * MM + m;
  float dtv = dt[idx], xv = x[idx], zv = z[idx];
#pragma unroll 2
  for (int lo = 0; lo < CLEN; ++lo) {
    float dtN = 0.f, xN = 0.f, zN = 0.f;
    if (lo + 1 < CLEN) {           // prefetch next timestep ahead of exp chain
      dtN = dt[idx + MM]; xN = x[idx + MM]; zN = z[idx + MM];
    }
    float4 Bv = *(const float4*)&bs[lo * 32 + dsub * 4];
    float4 Cv = *(const float4*)&bs[lo * 32 + DD + dsub * 4];
    float dtx = dtv * xv;
    h0_ = exp2f(dtv * A2v.x) * h0_ + dtx * Bv.x;
    h1_ = exp2f(dtv * A2v.y) * h1_ + dtx * Bv.y;
    h2_ = exp2f(dtv * A2v.z) * h2_ + dtx * Bv.z;
    h3_ = exp2f(dtv * A2v.w) * h3_ + dtx * Bv.w;
    float yp = h0_ * Cv.x + h1_ * Cv.y + h2_ * Cv.z + h3_ * Cv.w;
    yp += __shfl_xor(yp, 1);
    yp += __shfl_xor(yp, 2);
    if (dsub == 0) {
      float y = yp + Dpm * xv;
      float sig = 1.f / (1.f + exp2f(-LOG2E * zv));
      out[idx] = y * zv * sig;
    }
    dtv = dtN; xv = xN; zv = zN; idx += MM;
  }
}

extern "C" void kernel_launch(void* const* d_in, const int* in_sizes, int n_in,
                              void* d_out, int out_size, void* d_ws, size_t ws_size,
                              hipStream_t stream) {
  const float* x = (const float*)d_in[0];
  const float* z = (const float*)d_in[1];
  const float* W = (const float*)d_in[2];
  const float* dtW = (const float*)d_in[3];
  const float* dtb = (const float*)d_in[4];
  const float* A_log = (const float*)d_in[5];
  const float* Dp = (const float*)d_in[6];
  float* out = (float*)d_out;
  float* ws = (float*)d_ws;

  k_prep<<<320, 256, 0, stream>>>(dtW, A_log, ws);
  k_xp<<<(BLROWS / 16) * 6, 64, 0, stream>>>(x, W, ws);
  k_dt<<<1024, 256, 0, stream>>>(dtb, ws);
  k_scan1<<<16 * NCH * BB, 256, 0, stream>>>(x, ws);
  k_scan2<<<128, 256, 0, stream>>>(ws);
  k_scan3<<<16 * NCH * BB, 256, 0, stream>>>(x, z, Dp, out, ws);
}

// Round 6
// 108.061 us; speedup vs baseline: 2.0454x; 1.2384x over previous
//
#include <hip/hip_runtime.h>
#include <math.h>

#define BB 2
#define LL 2048
#define MM 1024
#define DD 16
#define RR 64
#define NN 96
#define BLROWS (BB*LL)          // 4096
#define NCH 64                  // chunks
#define CLEN (LL/NCH)           // 32

// workspace layout (float offsets)
#define OFF_XP    0
#define OFF_DT    (OFF_XP + BLROWS*NN)            // 393216
#define OFF_WT    (OFF_DT + BLROWS*MM)            // + 4194304 (unused now)
#define OFF_DTWT  (OFF_WT + MM*NN)                // + 98304
#define OFF_A2    (OFF_DTWT + RR*MM)              // + 65536
#define OFF_HEND  (OFF_A2 + MM*DD)                // + 16384
#define OFF_DTSUM (OFF_HEND + NCH*BB*MM*DD)       // + 2097152
// total = OFF_DTSUM + NCH*BB*MM = 6995968 floats = 28.0 MB

typedef __attribute__((ext_vector_type(8))) short bf16x8;
typedef __attribute__((ext_vector_type(4))) float f32x4;

// fast softplus: log(1+e^v) via native v_exp/v_log
__device__ __forceinline__ float softplusf(float v) {
  return v > 20.f ? v : __logf(1.f + __expf(v));
}

// f32 -> bf16 round-to-nearest-even
__device__ __forceinline__ short f2bf(float f) {
  union { float f; unsigned u; } v; v.f = f;
  unsigned r = v.u + 0x7FFFu + ((v.u >> 16) & 1u);
  return (short)(r >> 16);
}

// ---------------- prep: dtW transpose + A2 = -exp(A_log)^T (natural) ----------------
__global__ __launch_bounds__(256) void k_prep(const float* __restrict__ dtW,
                                              const float* __restrict__ A_log,
                                              float* __restrict__ ws) {
  int idx = blockIdx.x * 256 + threadIdx.x;
  if (idx < RR * MM) {
    int r = idx / MM, m = idx % MM;
    ws[OFF_DTWT + idx] = dtW[m * RR + r];
  } else if (idx < RR * MM + MM * DD) {
    int j = idx - RR * MM;
    int m = j / DD, d = j % DD;
    ws[OFF_A2 + j] = -__expf(A_log[d * MM + m]);
  }
}

// ---------------- xp = x @ W^T  (4096 x 96, K=1024) via bf16 MFMA ----------------
__global__ __launch_bounds__(64) void k_xp(const float* __restrict__ x,
                                           const float* __restrict__ W,
                                           float* __restrict__ ws) {
  float* xp = ws + OFF_XP;
  int lane = threadIdx.x;
  int rt = blockIdx.x / 6, nt = blockIdx.x % 6;
  int lr = lane & 15, lk = lane >> 4;
  const float* xr = x + (size_t)(rt * 16 + lr) * MM + lk * 8;
  const float* wr = W + (size_t)(nt * 16 + lr) * MM + lk * 8;
  f32x4 acc = {0.f, 0.f, 0.f, 0.f};
#pragma unroll 4
  for (int kk = 0; kk < MM; kk += 32) {
    float4 xa = *(const float4*)(xr + kk);
    float4 xb = *(const float4*)(xr + kk + 4);
    float4 wa = *(const float4*)(wr + kk);
    float4 wb = *(const float4*)(wr + kk + 4);
    bf16x8 a, b;
    a[0] = f2bf(xa.x); a[1] = f2bf(xa.y); a[2] = f2bf(xa.z); a[3] = f2bf(xa.w);
    a[4] = f2bf(xb.x); a[5] = f2bf(xb.y); a[6] = f2bf(xb.z); a[7] = f2bf(xb.w);
    b[0] = f2bf(wa.x); b[1] = f2bf(wa.y); b[2] = f2bf(wa.z); b[3] = f2bf(wa.w);
    b[4] = f2bf(wb.x); b[5] = f2bf(wb.y); b[6] = f2bf(wb.z); b[7] = f2bf(wb.w);
    acc = __builtin_amdgcn_mfma_f32_16x16x32_bf16(a, b, acc, 0, 0, 0);
  }
  int r0 = rt * 16 + lk * 4, c = nt * 16 + lr;
#pragma unroll
  for (int e = 0; e < 4; ++e)
    xp[(size_t)(r0 + e) * NN + c] = acc[e];
}

// ---------------- dt = softplus(xp[:, :64] @ dtW^T + b)  (4096 x 1024, K=64) ----------------
__global__ __launch_bounds__(256) void k_dt(const float* __restrict__ dtb,
                                            float* __restrict__ ws) {
  const float* xp = ws + OFF_XP;
  const float4* dtWt4 = (const float4*)(ws + OFF_DTWT); // [r][256] float4
  float* dt = ws + OFF_DT;
  __shared__ float xs[16 * 64];
  int mb = blockIdx.x & 3;
  int bl0 = (blockIdx.x >> 2) * 16;
  int t = threadIdx.x;
  {
    int r = t >> 4, c4 = t & 15;
    *(float4*)&xs[r * 64 + c4 * 4] = *(const float4*)&xp[(size_t)(bl0 + r) * NN + c4 * 4];
  }
  __syncthreads();
  int mt = t & 63, rg = t >> 6;
  int m4 = mb * 64 + mt;   // float4 index into m (0..255)
  float acc[4][4] = {};
  for (int k4 = 0; k4 < 16; ++k4) {
    float4 w0 = dtWt4[(k4 * 4 + 0) * 256 + m4];
    float4 w1 = dtWt4[(k4 * 4 + 1) * 256 + m4];
    float4 w2 = dtWt4[(k4 * 4 + 2) * 256 + m4];
    float4 w3 = dtWt4[(k4 * 4 + 3) * 256 + m4];
#pragma unroll
    for (int r = 0; r < 4; ++r) {
      float4 xv = *(const float4*)&xs[(rg * 4 + r) * 64 + k4 * 4];
      acc[r][0] += xv.x * w0.x + xv.y * w1.x + xv.z * w2.x + xv.w * w3.x;
      acc[r][1] += xv.x * w0.y + xv.y * w1.y + xv.z * w2.y + xv.w * w3.y;
      acc[r][2] += xv.x * w0.z + xv.y * w1.z + xv.z * w2.z + xv.w * w3.z;
      acc[r][3] += xv.x * w0.w + xv.y * w1.w + xv.z * w2.w + xv.w * w3.w;
    }
  }
  float4 bv = *(const float4*)&dtb[m4 * 4];
#pragma unroll
  for (int r = 0; r < 4; ++r) {
    float4 o;
    o.x = softplusf(acc[r][0] + bv.x);
    o.y = softplusf(acc[r][1] + bv.y);
    o.z = softplusf(acc[r][2] + bv.z);
    o.w = softplusf(acc[r][3] + bv.w);
    *(float4*)&dt[(size_t)(bl0 + rg * 4 + r) * MM + m4 * 4] = o;
  }
}

// ---------------- scan phase 1: per-chunk h_end and sum(dt) ----------------
// d-split: thread = (m, d-quartet). grid (MM/64)*NCH*BB = 2048 wgs, block 256.
// dt/x chunk tiles staged in LDS (coalesced), inner loop is LDS-only.
__global__ __launch_bounds__(256) void k_scan1(const float* __restrict__ x,
                                               float* __restrict__ ws) {
  const float* xp = ws + OFF_XP;
  const float* A2t = ws + OFF_A2;
  float* hend = ws + OFF_HEND;
  float* dtsum = ws + OFF_DTSUM;
  __shared__ __align__(16) float ds_[CLEN * 64];
  __shared__ __align__(16) float xs_[CLEN * 64];
  __shared__ __align__(16) float bs[CLEN * DD];
  int wg = blockIdx.x;
  int mw = wg & 15, c = (wg >> 4) & (NCH - 1), b = wg >> 10;
  int t = threadIdx.x;
  int ml = t >> 2, dsub = t & 3;
  int m0 = mw * 64, m = m0 + ml;
  int l0 = c * CLEN;
  const float* dtg = ws + OFF_DT + (size_t)(b * LL + l0) * MM + m0;
  const float* xg = x + (size_t)(b * LL + l0) * MM + m0;
#pragma unroll
  for (int i = t; i < CLEN * 16; i += 256) {
    int lo = i >> 4, q = i & 15;
    *(float4*)&ds_[i * 4] = *(const float4*)&dtg[(size_t)lo * MM + q * 4];
    *(float4*)&xs_[i * 4] = *(const float4*)&xg[(size_t)lo * MM + q * 4];
  }
  for (int i = t; i < CLEN * DD; i += 256) {
    int r = i >> 4, cc = i & 15;
    bs[i] = xp[(size_t)(b * LL + l0 + r) * NN + RR + cc];
  }
  __syncthreads();
  float4 A2v = *(const float4*)&A2t[m * DD + dsub * 4];
  float h0_ = 0.f, h1_ = 0.f, h2_ = 0.f, h3_ = 0.f, S = 0.f;
#pragma unroll 4
  for (int lo = 0; lo < CLEN; ++lo) {
    float dtv = ds_[lo * 64 + ml];
    float xv = xs_[lo * 64 + ml];
    float4 Bv = *(const float4*)&bs[lo * DD + dsub * 4];
    S += dtv;
    float dtx = dtv * xv;
    h0_ = __expf(dtv * A2v.x) * h0_ + dtx * Bv.x;
    h1_ = __expf(dtv * A2v.y) * h1_ + dtx * Bv.y;
    h2_ = __expf(dtv * A2v.z) * h2_ + dtx * Bv.z;
    h3_ = __expf(dtv * A2v.w) * h3_ + dtx * Bv.w;
  }
  size_t o = ((size_t)((c * BB + b) * MM + m)) * DD + dsub * 4;
  *(float4*)&hend[o] = make_float4(h0_, h1_, h2_, h3_);
  if (dsub == 0) dtsum[(c * BB + b) * MM + m] = S;
}

// ---------------- scan phase 2: scan over chunks (software-pipelined), h0 in place ----------------
__global__ __launch_bounds__(256) void k_scan2(float* __restrict__ ws) {
  int t = blockIdx.x * 256 + threadIdx.x; // 32768 threads
  int d = t & 15, m = (t >> 4) & 1023, b = t >> 14;
  float* hend = ws + OFF_HEND;
  const float* dtsum = ws + OFF_DTSUM;
  float A2 = ws[OFF_A2 + m * DD + d];
  const size_t hstride = (size_t)BB * MM * DD;
  const int sstride = BB * MM;
  size_t o = ((size_t)b * MM + m) * DD + d;
  int si = b * MM + m;
  float h = 0.f;
  float he = hend[o], S = dtsum[si];
  for (int c = 0; c < NCH; ++c) {
    float heN = 0.f, SN = 0.f;
    if (c + 1 < NCH) {
      heN = hend[o + hstride];
      SN = dtsum[si + sstride];
    }
    hend[o] = h;                  // h0 for chunk c
    h = __expf(A2 * S) * h + he;
    he = heN; S = SN;
    o += hstride; si += sstride;
  }
}

// ---------------- scan phase 3: recompute with h0, emit y * silu(z). d-split x4 ----------------
// dt/x/z chunk tiles staged in LDS (coalesced); inner loop LDS + VALU only.
__global__ __launch_bounds__(256) void k_scan3(const float* __restrict__ x,
                                               const float* __restrict__ z,
                                               const float* __restrict__ Dp,
                                               float* __restrict__ out,
                                               float* __restrict__ ws) {
  const float* xp = ws + OFF_XP;
  const float* A2t = ws + OFF_A2;
  const float* h0w = ws + OFF_HEND;      // phase 2 left h0 here
  __shared__ __align__(16) float ds_[CLEN * 64];
  __shared__ __align__(16) float xs_[CLEN * 64];
  __shared__ __align__(16) float zs_[CLEN * 64];
  __shared__ __align__(16) float bs[CLEN * 32];
  int wg = blockIdx.x;
  int mw = wg & 15, c = (wg >> 4) & (NCH - 1), b = wg >> 10;
  int t = threadIdx.x;
  int ml = t >> 2, dsub = t & 3;
  int m0 = mw * 64, m = m0 + ml;
  int l0 = c * CLEN;
  const float* dtg = ws + OFF_DT + (size_t)(b * LL + l0) * MM + m0;
  const float* xg = x + (size_t)(b * LL + l0) * MM + m0;
  const float* zg = z + (size_t)(b * LL + l0) * MM + m0;
#pragma unroll
  for (int i = t; i < CLEN * 16; i += 256) {
    int lo = i >> 4, q = i & 15;
    *(float4*)&ds_[i * 4] = *(const float4*)&dtg[(size_t)lo * MM + q * 4];
    *(float4*)&xs_[i * 4] = *(const float4*)&xg[(size_t)lo * MM + q * 4];
    *(float4*)&zs_[i * 4] = *(const float4*)&zg[(size_t)lo * MM + q * 4];
  }
  for (int i = t; i < CLEN * 32; i += 256) {
    int r = i >> 5, cc = i & 31;
    bs[i] = xp[(size_t)(b * LL + l0 + r) * NN + RR + cc];
  }
  __syncthreads();
  float4 A2v = *(const float4*)&A2t[m * DD + dsub * 4];
  size_t o = ((size_t)((c * BB + b) * MM + m)) * DD + dsub * 4;
  float4 hv = *(const float4*)&h0w[o];
  float h0_ = hv.x, h1_ = hv.y, h2_ = hv.z, h3_ = hv.w;
  float Dpm = Dp[m];
  size_t idx = ((size_t)(b * LL + l0)) * MM + m;
#pragma unroll 4
  for (int lo = 0; lo < CLEN; ++lo) {
    float dtv = ds_[lo * 64 + ml];
    float xv = xs_[lo * 64 + ml];
    float zv = zs_[lo * 64 + ml];
    float4 Bv = *(const float4*)&bs[lo * 32 + dsub * 4];
    float4 Cv = *(const float4*)&bs[lo * 32 + DD + dsub * 4];
    float dtx = dtv * xv;
    h0_ = __expf(dtv * A2v.x) * h0_ + dtx * Bv.x;
    h1_ = __expf(dtv * A2v.y) * h1_ + dtx * Bv.y;
    h2_ = __expf(dtv * A2v.z) * h2_ + dtx * Bv.z;
    h3_ = __expf(dtv * A2v.w) * h3_ + dtx * Bv.w;
    float yp = h0_ * Cv.x + h1_ * Cv.y + h2_ * Cv.z + h3_ * Cv.w;
    yp += __shfl_xor(yp, 1);
    yp += __shfl_xor(yp, 2);
    float sig = __builtin_amdgcn_rcpf(1.f + __expf(-zv));
    if (dsub == 0)
      out[idx + (size_t)lo * MM] = (yp + Dpm * xv) * zv * sig;
  }
}

extern "C" void kernel_launch(void* const* d_in, const int* in_sizes, int n_in,
                              void* d_out, int out_size, void* d_ws, size_t ws_size,
                              hipStream_t stream) {
  const float* x = (const float*)d_in[0];
  const float* z = (const float*)d_in[1];
  const float* W = (const float*)d_in[2];
  const float* dtW = (const float*)d_in[3];
  const float* dtb = (const float*)d_in[4];
  const float* A_log = (const float*)d_in[5];
  const float* Dp = (const float*)d_in[6];
  float* out = (float*)d_out;
  float* ws = (float*)d_ws;

  k_prep<<<320, 256, 0, stream>>>(dtW, A_log, ws);
  k_xp<<<(BLROWS / 16) * 6, 64, 0, stream>>>(x, W, ws);
  k_dt<<<1024, 256, 0, stream>>>(dtb, ws);
  k_scan1<<<16 * NCH * BB, 256, 0, stream>>>(x, ws);
  k_scan2<<<128, 256, 0, stream>>>(ws);
  k_scan3<<<16 * NCH * BB, 256, 0, stream>>>(x, z, Dp, out, ws);
}

// Round 7
// 87.974 us; speedup vs baseline: 2.5125x; 1.2283x over previous
//
#include <hip/hip_runtime.h>
#include <math.h>

#define BB 2
#define LL 2048
#define MM 1024
#define DD 16
#define RR 64
#define NN 96
#define BLROWS (BB*LL)          // 4096
#define NCH 64                  // chunks
#define CLEN (LL/NCH)           // 32

// workspace layout (float offsets). dt region holds bf16 (ushort), 2 per float slot.
#define OFF_XP    0
#define OFF_DT    (OFF_XP + BLROWS*NN)            // 393216
#define OFF_A2    (OFF_DT + BLROWS*MM/2)          // + 2097152
#define OFF_HEND  (OFF_A2 + MM*DD)                // + 16384
#define OFF_DTSUM (OFF_HEND + NCH*BB*MM*DD)       // + 2097152
// total = OFF_DTSUM + NCH*BB*MM = 4735232 floats = 18.9 MB

typedef __attribute__((ext_vector_type(8))) short bf16x8;
typedef __attribute__((ext_vector_type(4))) float f32x4;
typedef __attribute__((ext_vector_type(4))) unsigned short u16x4;

// fast softplus: log(1+e^v) via native v_exp/v_log
__device__ __forceinline__ float softplusf(float v) {
  return v > 20.f ? v : __logf(1.f + __expf(v));
}

// f32 -> bf16 round-to-nearest-even
__device__ __forceinline__ short f2bf(float f) {
  union { float f; unsigned u; } v; v.f = f;
  unsigned r = v.u + 0x7FFFu + ((v.u >> 16) & 1u);
  return (short)(r >> 16);
}

__device__ __forceinline__ float bf2f(unsigned short u) {
  return __uint_as_float((unsigned)u << 16);
}

// ---------------- xp = x @ W^T (4096 x 96, K=1024) via bf16 MFMA ----------------
// blocks [0,768): GEMM, one wave per 16-row x 32-col tile (2 n-tiles, A loaded once).
// blocks [768,1024): A2 = -exp(A_log)^T prep (16384 elems).
#define XP_GEMM_BLOCKS ((BLROWS/16)*3)   // 768
__global__ __launch_bounds__(64) void k_xp(const float* __restrict__ x,
                                           const float* __restrict__ W,
                                           const float* __restrict__ A_log,
                                           float* __restrict__ ws) {
  if (blockIdx.x >= XP_GEMM_BLOCKS) {
    int idx = (blockIdx.x - XP_GEMM_BLOCKS) * 64 + threadIdx.x;
    int m = idx >> 4, d = idx & 15;
    ws[OFF_A2 + idx] = -__expf(A_log[d * MM + m]);
    return;
  }
  float* xp = ws + OFF_XP;
  int lane = threadIdx.x;
  int rt = blockIdx.x / 3, np = blockIdx.x % 3;
  int lr = lane & 15, lk = lane >> 4;
  const float* xr = x + (size_t)(rt * 16 + lr) * MM + lk * 8;
  const float* wr0 = W + (size_t)(np * 32 + lr) * MM + lk * 8;
  const float* wr1 = W + (size_t)(np * 32 + 16 + lr) * MM + lk * 8;
  f32x4 acc0 = {0.f, 0.f, 0.f, 0.f}, acc1 = {0.f, 0.f, 0.f, 0.f};
#pragma unroll 2
  for (int kk = 0; kk < MM; kk += 32) {
    float4 xa = *(const float4*)(xr + kk);
    float4 xb = *(const float4*)(xr + kk + 4);
    float4 p0 = *(const float4*)(wr0 + kk);
    float4 p1 = *(const float4*)(wr0 + kk + 4);
    float4 q0 = *(const float4*)(wr1 + kk);
    float4 q1 = *(const float4*)(wr1 + kk + 4);
    bf16x8 a, b0, b1;
    a[0] = f2bf(xa.x); a[1] = f2bf(xa.y); a[2] = f2bf(xa.z); a[3] = f2bf(xa.w);
    a[4] = f2bf(xb.x); a[5] = f2bf(xb.y); a[6] = f2bf(xb.z); a[7] = f2bf(xb.w);
    b0[0] = f2bf(p0.x); b0[1] = f2bf(p0.y); b0[2] = f2bf(p0.z); b0[3] = f2bf(p0.w);
    b0[4] = f2bf(p1.x); b0[5] = f2bf(p1.y); b0[6] = f2bf(p1.z); b0[7] = f2bf(p1.w);
    b1[0] = f2bf(q0.x); b1[1] = f2bf(q0.y); b1[2] = f2bf(q0.z); b1[3] = f2bf(q0.w);
    b1[4] = f2bf(q1.x); b1[5] = f2bf(q1.y); b1[6] = f2bf(q1.z); b1[7] = f2bf(q1.w);
    acc0 = __builtin_amdgcn_mfma_f32_16x16x32_bf16(a, b0, acc0, 0, 0, 0);
    acc1 = __builtin_amdgcn_mfma_f32_16x16x32_bf16(a, b1, acc1, 0, 0, 0);
  }
  int r0 = rt * 16 + lk * 4, c0 = np * 32 + lr;
#pragma unroll
  for (int e = 0; e < 4; ++e) {
    xp[(size_t)(r0 + e) * NN + c0] = acc0[e];
    xp[(size_t)(r0 + e) * NN + c0 + 16] = acc1[e];
  }
}

// ---------------- dt = softplus(xp[:, :64] @ dtW^T + b), bf16 out, via MFMA ----------------
// One wave per 16-row x 128-m strip: A-fragment (xp rows, K=64) loaded once,
// 8 m-tiles x 2 MFMA. dtW rows are K-contiguous -> native B fragments, no prep.
__global__ __launch_bounds__(64) void k_dt(const float* __restrict__ dtW,
                                           const float* __restrict__ dtb,
                                           float* __restrict__ ws) {
  const float* xp = ws + OFF_XP;
  unsigned short* dt16 = (unsigned short*)(ws + OFF_DT);
  int lane = threadIdx.x;
  int rt = blockIdx.x >> 3, mg = blockIdx.x & 7;
  int lr = lane & 15, lk = lane >> 4;
  const float* xr = xp + (size_t)(rt * 16 + lr) * NN + lk * 8;
  bf16x8 a0, a1;
  {
    float4 xa = *(const float4*)(xr);
    float4 xb = *(const float4*)(xr + 4);
    float4 xc = *(const float4*)(xr + 32);
    float4 xd = *(const float4*)(xr + 36);
    a0[0] = f2bf(xa.x); a0[1] = f2bf(xa.y); a0[2] = f2bf(xa.z); a0[3] = f2bf(xa.w);
    a0[4] = f2bf(xb.x); a0[5] = f2bf(xb.y); a0[6] = f2bf(xb.z); a0[7] = f2bf(xb.w);
    a1[0] = f2bf(xc.x); a1[1] = f2bf(xc.y); a1[2] = f2bf(xc.z); a1[3] = f2bf(xc.w);
    a1[4] = f2bf(xd.x); a1[5] = f2bf(xd.y); a1[6] = f2bf(xd.z); a1[7] = f2bf(xd.w);
  }
  int r0 = rt * 16 + lk * 4;
#pragma unroll 2
  for (int mt = 0; mt < 8; ++mt) {
    int mcol = (mg * 8 + mt) * 16 + lr;
    const float* wr = dtW + (size_t)mcol * RR + lk * 8;
    float4 p0 = *(const float4*)(wr);
    float4 p1 = *(const float4*)(wr + 4);
    float4 p2 = *(const float4*)(wr + 32);
    float4 p3 = *(const float4*)(wr + 36);
    bf16x8 b0, b1;
    b0[0] = f2bf(p0.x); b0[1] = f2bf(p0.y); b0[2] = f2bf(p0.z); b0[3] = f2bf(p0.w);
    b0[4] = f2bf(p1.x); b0[5] = f2bf(p1.y); b0[6] = f2bf(p1.z); b0[7] = f2bf(p1.w);
    b1[0] = f2bf(p2.x); b1[1] = f2bf(p2.y); b1[2] = f2bf(p2.z); b1[3] = f2bf(p2.w);
    b1[4] = f2bf(p3.x); b1[5] = f2bf(p3.y); b1[6] = f2bf(p3.z); b1[7] = f2bf(p3.w);
    f32x4 acc = {0.f, 0.f, 0.f, 0.f};
    acc = __builtin_amdgcn_mfma_f32_16x16x32_bf16(a0, b0, acc, 0, 0, 0);
    acc = __builtin_amdgcn_mfma_f32_16x16x32_bf16(a1, b1, acc, 0, 0, 0);
    float bv = dtb[mcol];
#pragma unroll
    for (int e = 0; e < 4; ++e)
      dt16[(size_t)(r0 + e) * MM + mcol] = (unsigned short)f2bf(softplusf(acc[e] + bv));
  }
}

// ---------------- scan phase 1: per-chunk h_end and sum(dt) ----------------
// d-split: thread = (m, d-quartet). grid 16*NCH*BB = 2048 wgs, block 256.
// dt(bf16)/x chunk tiles staged into LDS as f32 (coalesced), inner loop LDS-only.
__global__ __launch_bounds__(256) void k_scan1(const float* __restrict__ x,
                                               float* __restrict__ ws) {
  const float* xp = ws + OFF_XP;
  const float* A2t = ws + OFF_A2;
  float* hend = ws + OFF_HEND;
  float* dtsum = ws + OFF_DTSUM;
  __shared__ __align__(16) float ds_[CLEN * 64];
  __shared__ __align__(16) float xs_[CLEN * 64];
  __shared__ __align__(16) float bs[CLEN * DD];
  int wg = blockIdx.x;
  int mw = wg & 15, c = (wg >> 4) & (NCH - 1), b = wg >> 10;
  int t = threadIdx.x;
  int ml = t >> 2, dsub = t & 3;
  int m0 = mw * 64, m = m0 + ml;
  int l0 = c * CLEN;
  const unsigned short* dtg = (const unsigned short*)(ws + OFF_DT) + (size_t)(b * LL + l0) * MM + m0;
  const float* xg = x + (size_t)(b * LL + l0) * MM + m0;
#pragma unroll
  for (int i = t; i < CLEN * 16; i += 256) {
    int lo = i >> 4, q = i & 15;
    u16x4 dv = *(const u16x4*)&dtg[(size_t)lo * MM + q * 4];
    *(float4*)&ds_[lo * 64 + q * 4] = make_float4(bf2f(dv[0]), bf2f(dv[1]), bf2f(dv[2]), bf2f(dv[3]));
    *(float4*)&xs_[lo * 64 + q * 4] = *(const float4*)&xg[(size_t)lo * MM + q * 4];
  }
  for (int i = t; i < CLEN * DD; i += 256) {
    int r = i >> 4, cc = i & 15;
    bs[i] = xp[(size_t)(b * LL + l0 + r) * NN + RR + cc];
  }
  __syncthreads();
  float4 A2v = *(const float4*)&A2t[m * DD + dsub * 4];
  float h0_ = 0.f, h1_ = 0.f, h2_ = 0.f, h3_ = 0.f, S = 0.f;
#pragma unroll 4
  for (int lo = 0; lo < CLEN; ++lo) {
    float dtv = ds_[lo * 64 + ml];
    float xv = xs_[lo * 64 + ml];
    float4 Bv = *(const float4*)&bs[lo * DD + dsub * 4];
    S += dtv;
    float dtx = dtv * xv;
    h0_ = __expf(dtv * A2v.x) * h0_ + dtx * Bv.x;
    h1_ = __expf(dtv * A2v.y) * h1_ + dtx * Bv.y;
    h2_ = __expf(dtv * A2v.z) * h2_ + dtx * Bv.z;
    h3_ = __expf(dtv * A2v.w) * h3_ + dtx * Bv.w;
  }
  size_t o = ((size_t)((c * BB + b) * MM + m)) * DD + dsub * 4;
  *(float4*)&hend[o] = make_float4(h0_, h1_, h2_, h3_);
  if (dsub == 0) dtsum[(c * BB + b) * MM + m] = S;
}

// ---------------- scan phase 2: scan over chunks (software-pipelined), h0 in place ----------------
__global__ __launch_bounds__(256) void k_scan2(float* __restrict__ ws) {
  int t = blockIdx.x * 256 + threadIdx.x; // 32768 threads
  int d = t & 15, m = (t >> 4) & 1023, b = t >> 14;
  float* hend = ws + OFF_HEND;
  const float* dtsum = ws + OFF_DTSUM;
  float A2 = ws[OFF_A2 + m * DD + d];
  const size_t hstride = (size_t)BB * MM * DD;
  const int sstride = BB * MM;
  size_t o = ((size_t)b * MM + m) * DD + d;
  int si = b * MM + m;
  float h = 0.f;
  float he = hend[o], S = dtsum[si];
  for (int c = 0; c < NCH; ++c) {
    float heN = 0.f, SN = 0.f;
    if (c + 1 < NCH) {
      heN = hend[o + hstride];
      SN = dtsum[si + sstride];
    }
    hend[o] = h;                  // h0 for chunk c
    h = __expf(A2 * S) * h + he;
    he = heN; S = SN;
    o += hstride; si += sstride;
  }
}

// ---------------- scan phase 3: recompute with h0, emit y * silu(z). d-split x4 ----------------
__global__ __launch_bounds__(256) void k_scan3(const float* __restrict__ x,
                                               const float* __restrict__ z,
                                               const float* __restrict__ Dp,
                                               float* __restrict__ out,
                                               float* __restrict__ ws) {
  const float* xp = ws + OFF_XP;
  const float* A2t = ws + OFF_A2;
  const float* h0w = ws + OFF_HEND;      // phase 2 left h0 here
  __shared__ __align__(16) float ds_[CLEN * 64];
  __shared__ __align__(16) float xs_[CLEN * 64];
  __shared__ __align__(16) float zs_[CLEN * 64];
  __shared__ __align__(16) float bs[CLEN * 32];
  int wg = blockIdx.x;
  int mw = wg & 15, c = (wg >> 4) & (NCH - 1), b = wg >> 10;
  int t = threadIdx.x;
  int ml = t >> 2, dsub = t & 3;
  int m0 = mw * 64, m = m0 + ml;
  int l0 = c * CLEN;
  const unsigned short* dtg = (const unsigned short*)(ws + OFF_DT) + (size_t)(b * LL + l0) * MM + m0;
  const float* xg = x + (size_t)(b * LL + l0) * MM + m0;
  const float* zg = z + (size_t)(b * LL + l0) * MM + m0;
#pragma unroll
  for (int i = t; i < CLEN * 16; i += 256) {
    int lo = i >> 4, q = i & 15;
    u16x4 dv = *(const u16x4*)&dtg[(size_t)lo * MM + q * 4];
    *(float4*)&ds_[lo * 64 + q * 4] = make_float4(bf2f(dv[0]), bf2f(dv[1]), bf2f(dv[2]), bf2f(dv[3]));
    *(float4*)&xs_[lo * 64 + q * 4] = *(const float4*)&xg[(size_t)lo * MM + q * 4];
    *(float4*)&zs_[lo * 64 + q * 4] = *(const float4*)&zg[(size_t)lo * MM + q * 4];
  }
  for (int i = t; i < CLEN * 32; i += 256) {
    int r = i >> 5, cc = i & 31;
    bs[i] = xp[(size_t)(b * LL + l0 + r) * NN + RR + cc];
  }
  __syncthreads();
  float4 A2v = *(const float4*)&A2t[m * DD + dsub * 4];
  size_t o = ((size_t)((c * BB + b) * MM + m)) * DD + dsub * 4;
  float4 hv = *(const float4*)&h0w[o];
  float h0_ = hv.x, h1_ = hv.y, h2_ = hv.z, h3_ = hv.w;
  float Dpm = Dp[m];
  size_t idx = ((size_t)(b * LL + l0)) * MM + m;
#pragma unroll 4
  for (int lo = 0; lo < CLEN; ++lo) {
    float dtv = ds_[lo * 64 + ml];
    float xv = xs_[lo * 64 + ml];
    float zv = zs_[lo * 64 + ml];
    float4 Bv = *(const float4*)&bs[lo * 32 + dsub * 4];
    float4 Cv = *(const float4*)&bs[lo * 32 + DD + dsub * 4];
    float dtx = dtv * xv;
    h0_ = __expf(dtv * A2v.x) * h0_ + dtx * Bv.x;
    h1_ = __expf(dtv * A2v.y) * h1_ + dtx * Bv.y;
    h2_ = __expf(dtv * A2v.z) * h2_ + dtx * Bv.z;
    h3_ = __expf(dtv * A2v.w) * h3_ + dtx * Bv.w;
    float yp = h0_ * Cv.x + h1_ * Cv.y + h2_ * Cv.z + h3_ * Cv.w;
    yp += __shfl_xor(yp, 1);
    yp += __shfl_xor(yp, 2);
    float sig = __builtin_amdgcn_rcpf(1.f + __expf(-zv));
    if (dsub == 0)
      out[idx + (size_t)lo * MM] = (yp + Dpm * xv) * zv * sig;
  }
}

extern "C" void kernel_launch(void* const* d_in, const int* in_sizes, int n_in,
                              void* d_out, int out_size, void* d_ws, size_t ws_size,
                              hipStream_t stream) {
  const float* x = (const float*)d_in[0];
  const float* z = (const float*)d_in[1];
  const float* W = (const float*)d_in[2];
  const float* dtW = (const float*)d_in[3];
  const float* dtb = (const float*)d_in[4];
  const float* A_log = (const float*)d_in[5];
  const float* Dp = (const float*)d_in[6];
  float* out = (float*)d_out;
  float* ws = (float*)d_ws;

  k_xp<<<XP_GEMM_BLOCKS + (MM * DD / 64), 64, 0, stream>>>(x, W, A_log, ws);
  k_dt<<<(BLROWS / 16) * 8, 64, 0, stream>>>(dtW, dtb, ws);
  k_scan1<<<16 * NCH * BB, 256, 0, stream>>>(x, ws);
  k_scan2<<<128, 256, 0, stream>>>(ws);
  k_scan3<<<16 * NCH * BB, 256, 0, stream>>>(x, z, Dp, out, ws);
}

// Round 9
// 85.962 us; speedup vs baseline: 2.5713x; 1.0234x over previous
//
#include <hip/hip_runtime.h>
#include <math.h>

#define BB 2
#define LL 2048
#define MM 1024
#define DD 16
#define RR 64
#define NN 96
#define BLROWS (BB*LL)          // 4096
#define NCH 64                  // chunks
#define CLEN (LL/NCH)           // 32

// workspace layout (float offsets). dt region holds bf16 (ushort), 2 per float slot.
#define OFF_XP    0
#define OFF_DT    (OFF_XP + BLROWS*NN)            // 393216
#define OFF_A2    (OFF_DT + BLROWS*MM/2)          // + 2097152
#define OFF_HEND  (OFF_A2 + MM*DD)                // + 16384
#define OFF_DTSUM (OFF_HEND + NCH*BB*MM*DD)       // + 2097152
// total = OFF_DTSUM + NCH*BB*MM = 4735232 floats = 18.9 MB

typedef __attribute__((ext_vector_type(8))) short bf16x8;
typedef __attribute__((ext_vector_type(4))) float f32x4;
typedef __attribute__((ext_vector_type(4))) unsigned short u16x4;

union BF8 { bf16x8 v; unsigned u[4]; };

// packed f32x2 -> bf16x2 (RNE) in one instruction
__device__ __forceinline__ unsigned cvtpk(float a, float b) {
  unsigned r;
  asm("v_cvt_pk_bf16_f32 %0, %1, %2" : "=v"(r) : "v"(a), "v"(b));
  return r;
}

// fast softplus: log(1+e^v) via native v_exp/v_log
__device__ __forceinline__ float softplusf(float v) {
  return v > 20.f ? v : __logf(1.f + __expf(v));
}

// f32 -> bf16 round-to-nearest-even (scalar)
__device__ __forceinline__ short f2bf(float f) {
  union { float f; unsigned u; } v; v.f = f;
  unsigned r = v.u + 0x7FFFu + ((v.u >> 16) & 1u);
  return (short)(r >> 16);
}

__device__ __forceinline__ float bf2f(unsigned short u) {
  return __uint_as_float((unsigned)u << 16);
}

// cross-lane xor-1 / xor-2 via DPP quad_perm (VALU pipe, not LDS pipe)
__device__ __forceinline__ float dpp_xor1(float v) {
  int i = __builtin_amdgcn_mov_dpp(__float_as_int(v), 0xB1, 0xF, 0xF, true);
  return __int_as_float(i);
}
__device__ __forceinline__ float dpp_xor2(float v) {
  int i = __builtin_amdgcn_mov_dpp(__float_as_int(v), 0x4E, 0xF, 0xF, true);
  return __int_as_float(i);
}

// ---------------- xp = x @ W^T (4096 x 96, K=1024) via bf16 MFMA ----------------
// blocks [0,768): GEMM, one wave per 16-row x 32-col tile (2 n-tiles, A loaded once).
// blocks [768,1024): A2 = -exp(A_log)^T prep (16384 elems).
#define XP_GEMM_BLOCKS ((BLROWS/16)*3)   // 768
__global__ __launch_bounds__(64) void k_xp(const float* __restrict__ x,
                                           const float* __restrict__ W,
                                           const float* __restrict__ A_log,
                                           float* __restrict__ ws) {
  if (blockIdx.x >= XP_GEMM_BLOCKS) {
    int idx = (blockIdx.x - XP_GEMM_BLOCKS) * 64 + threadIdx.x;
    int m = idx >> 4, d = idx & 15;
    ws[OFF_A2 + idx] = -__expf(A_log[d * MM + m]);
    return;
  }
  float* xp = ws + OFF_XP;
  int lane = threadIdx.x;
  int rt = blockIdx.x / 3, np = blockIdx.x % 3;
  int lr = lane & 15, lk = lane >> 4;
  const float* xr = x + (size_t)(rt * 16 + lr) * MM + lk * 8;
  const float* wr0 = W + (size_t)(np * 32 + lr) * MM + lk * 8;
  const float* wr1 = W + (size_t)(np * 32 + 16 + lr) * MM + lk * 8;
  f32x4 acc0 = {0.f, 0.f, 0.f, 0.f}, acc1 = {0.f, 0.f, 0.f, 0.f};
#pragma unroll 2
  for (int kk = 0; kk < MM; kk += 32) {
    float4 xa = *(const float4*)(xr + kk);
    float4 xb = *(const float4*)(xr + kk + 4);
    float4 p0 = *(const float4*)(wr0 + kk);
    float4 p1 = *(const float4*)(wr0 + kk + 4);
    float4 q0 = *(const float4*)(wr1 + kk);
    float4 q1 = *(const float4*)(wr1 + kk + 4);
    BF8 a, b0, b1;
    a.u[0] = cvtpk(xa.x, xa.y); a.u[1] = cvtpk(xa.z, xa.w);
    a.u[2] = cvtpk(xb.x, xb.y); a.u[3] = cvtpk(xb.z, xb.w);
    b0.u[0] = cvtpk(p0.x, p0.y); b0.u[1] = cvtpk(p0.z, p0.w);
    b0.u[2] = cvtpk(p1.x, p1.y); b0.u[3] = cvtpk(p1.z, p1.w);
    b1.u[0] = cvtpk(q0.x, q0.y); b1.u[1] = cvtpk(q0.z, q0.w);
    b1.u[2] = cvtpk(q1.x, q1.y); b1.u[3] = cvtpk(q1.z, q1.w);
    acc0 = __builtin_amdgcn_mfma_f32_16x16x32_bf16(a.v, b0.v, acc0, 0, 0, 0);
    acc1 = __builtin_amdgcn_mfma_f32_16x16x32_bf16(a.v, b1.v, acc1, 0, 0, 0);
  }
  int r0 = rt * 16 + lk * 4, c0 = np * 32 + lr;
#pragma unroll
  for (int e = 0; e < 4; ++e) {
    xp[(size_t)(r0 + e) * NN + c0] = acc0[e];
    xp[(size_t)(r0 + e) * NN + c0 + 16] = acc1[e];
  }
}

// ---------------- dt = softplus(xp[:, :64] @ dtW^T + b), bf16 out, via MFMA ----------------
__global__ __launch_bounds__(64) void k_dt(const float* __restrict__ dtW,
                                           const float* __restrict__ dtb,
                                           float* __restrict__ ws) {
  const float* xp = ws + OFF_XP;
  unsigned short* dt16 = (unsigned short*)(ws + OFF_DT);
  int lane = threadIdx.x;
  int rt = blockIdx.x >> 3, mg = blockIdx.x & 7;
  int lr = lane & 15, lk = lane >> 4;
  const float* xr = xp + (size_t)(rt * 16 + lr) * NN + lk * 8;
  BF8 a0, a1;
  {
    float4 xa = *(const float4*)(xr);
    float4 xb = *(const float4*)(xr + 4);
    float4 xc = *(const float4*)(xr + 32);
    float4 xd = *(const float4*)(xr + 36);
    a0.u[0] = cvtpk(xa.x, xa.y); a0.u[1] = cvtpk(xa.z, xa.w);
    a0.u[2] = cvtpk(xb.x, xb.y); a0.u[3] = cvtpk(xb.z, xb.w);
    a1.u[0] = cvtpk(xc.x, xc.y); a1.u[1] = cvtpk(xc.z, xc.w);
    a1.u[2] = cvtpk(xd.x, xd.y); a1.u[3] = cvtpk(xd.z, xd.w);
  }
  int r0 = rt * 16 + lk * 4;
#pragma unroll 2
  for (int mt = 0; mt < 8; ++mt) {
    int mcol = (mg * 8 + mt) * 16 + lr;
    const float* wr = dtW + (size_t)mcol * RR + lk * 8;
    float4 p0 = *(const float4*)(wr);
    float4 p1 = *(const float4*)(wr + 4);
    float4 p2 = *(const float4*)(wr + 32);
    float4 p3 = *(const float4*)(wr + 36);
    BF8 b0, b1;
    b0.u[0] = cvtpk(p0.x, p0.y); b0.u[1] = cvtpk(p0.z, p0.w);
    b0.u[2] = cvtpk(p1.x, p1.y); b0.u[3] = cvtpk(p1.z, p1.w);
    b1.u[0] = cvtpk(p2.x, p2.y); b1.u[1] = cvtpk(p2.z, p2.w);
    b1.u[2] = cvtpk(p3.x, p3.y); b1.u[3] = cvtpk(p3.z, p3.w);
    f32x4 acc = {0.f, 0.f, 0.f, 0.f};
    acc = __builtin_amdgcn_mfma_f32_16x16x32_bf16(a0.v, b0.v, acc, 0, 0, 0);
    acc = __builtin_amdgcn_mfma_f32_16x16x32_bf16(a1.v, b1.v, acc, 0, 0, 0);
    float bv = dtb[mcol];
#pragma unroll
    for (int e = 0; e < 4; ++e)
      dt16[(size_t)(r0 + e) * MM + mcol] = (unsigned short)f2bf(softplusf(acc[e] + bv));
  }
}

// ---------------- scan phase 1: per-chunk h_end and sum(dt) ----------------
// d-split: thread = (m, d-quartet). grid 16*NCH*BB = 2048 wgs, block 256.
// dt(bf16)/x chunk tiles staged into LDS as f32 (coalesced), inner loop LDS-only.
__global__ __launch_bounds__(256) void k_scan1(const float* __restrict__ x,
                                               float* __restrict__ ws) {
  const float* xp = ws + OFF_XP;
  const float* A2t = ws + OFF_A2;
  float* hend = ws + OFF_HEND;
  float* dtsum = ws + OFF_DTSUM;
  __shared__ __align__(16) float ds_[CLEN * 64];
  __shared__ __align__(16) float xs_[CLEN * 64];
  __shared__ __align__(16) float bs[CLEN * DD];
  int wg = blockIdx.x;
  int mw = wg & 15, c = (wg >> 4) & (NCH - 1), b = wg >> 10;
  int t = threadIdx.x;
  int ml = t >> 2, dsub = t & 3;
  int m0 = mw * 64, m = m0 + ml;
  int l0 = c * CLEN;
  const unsigned short* dtg = (const unsigned short*)(ws + OFF_DT) + (size_t)(b * LL + l0) * MM + m0;
  const float* xg = x + (size_t)(b * LL + l0) * MM + m0;
#pragma unroll
  for (int i = t; i < CLEN * 16; i += 256) {
    int lo = i >> 4, q = i & 15;
    u16x4 dv = *(const u16x4*)&dtg[(size_t)lo * MM + q * 4];
    *(float4*)&ds_[lo * 64 + q * 4] = make_float4(bf2f(dv[0]), bf2f(dv[1]), bf2f(dv[2]), bf2f(dv[3]));
    *(float4*)&xs_[lo * 64 + q * 4] = *(const float4*)&xg[(size_t)lo * MM + q * 4];
  }
  for (int i = t; i < CLEN * DD; i += 256) {
    int r = i >> 4, cc = i & 15;
    bs[i] = xp[(size_t)(b * LL + l0 + r) * NN + RR + cc];
  }
  __syncthreads();
  float4 A2v = *(const float4*)&A2t[m * DD + dsub * 4];
  float h0_ = 0.f, h1_ = 0.f, h2_ = 0.f, h3_ = 0.f, S = 0.f;
#pragma unroll 4
  for (int lo = 0; lo < CLEN; ++lo) {
    float dtv = ds_[lo * 64 + ml];
    float xv = xs_[lo * 64 + ml];
    float4 Bv = *(const float4*)&bs[lo * DD + dsub * 4];
    S += dtv;
    float dtx = dtv * xv;
    h0_ = __expf(dtv * A2v.x) * h0_ + dtx * Bv.x;
    h1_ = __expf(dtv * A2v.y) * h1_ + dtx * Bv.y;
    h2_ = __expf(dtv * A2v.z) * h2_ + dtx * Bv.z;
    h3_ = __expf(dtv * A2v.w) * h3_ + dtx * Bv.w;
  }
  size_t o = ((size_t)((c * BB + b) * MM + m)) * DD + dsub * 4;
  *(float4*)&hend[o] = make_float4(h0_, h1_, h2_, h3_);
  if (dsub == 0) dtsum[(c * BB + b) * MM + m] = S;
}

// ---------------- scan phase 2: scan over chunks (software-pipelined), h0 in place ----------------
__global__ __launch_bounds__(256) void k_scan2(float* __restrict__ ws) {
  int t = blockIdx.x * 256 + threadIdx.x; // 32768 threads
  int d = t & 15, m = (t >> 4) & 1023, b = t >> 14;
  float* hend = ws + OFF_HEND;
  const float* dtsum = ws + OFF_DTSUM;
  float A2 = ws[OFF_A2 + m * DD + d];
  const size_t hstride = (size_t)BB * MM * DD;
  const int sstride = BB * MM;
  size_t o = ((size_t)b * MM + m) * DD + d;
  int si = b * MM + m;
  float h = 0.f;
  float he = hend[o], S = dtsum[si];
  for (int c = 0; c < NCH; ++c) {
    float heN = 0.f, SN = 0.f;
    if (c + 1 < NCH) {
      heN = hend[o + hstride];
      SN = dtsum[si + sstride];
    }
    hend[o] = h;                  // h0 for chunk c
    h = __expf(A2 * S) * h + he;
    he = heN; S = SN;
    o += hstride; si += sstride;
  }
}

// ---------------- scan phase 3: recompute with h0, emit y * silu(z). d-split x4 ----------------
__global__ __launch_bounds__(256) void k_scan3(const float* __restrict__ x,
                                               const float* __restrict__ z,
                                               const float* __restrict__ Dp,
                                               float* __restrict__ out,
                                               float* __restrict__ ws) {
  const float* xp = ws + OFF_XP;
  const float* A2t = ws + OFF_A2;
  const float* h0w = ws + OFF_HEND;      // phase 2 left h0 here
  __shared__ __align__(16) float ds_[CLEN * 64];
  __shared__ __align__(16) float xs_[CLEN * 64];
  __shared__ __align__(16) float zs_[CLEN * 64];
  __shared__ __align__(16) float bs[CLEN * 32];
  int wg = blockIdx.x;
  int mw = wg & 15, c = (wg >> 4) & (NCH - 1), b = wg >> 10;
  int t = threadIdx.x;
  int ml = t >> 2, dsub = t & 3;
  int m0 = mw * 64, m = m0 + ml;
  int l0 = c * CLEN;
  const unsigned short* dtg = (const unsigned short*)(ws + OFF_DT) + (size_t)(b * LL + l0) * MM + m0;
  const float* xg = x + (size_t)(b * LL + l0) * MM + m0;
  const float* zg = z + (size_t)(b * LL + l0) * MM + m0;
#pragma unroll
  for (int i = t; i < CLEN * 16; i += 256) {
    int lo = i >> 4, q = i & 15;
    u16x4 dv = *(const u16x4*)&dtg[(size_t)lo * MM + q * 4];
    *(float4*)&ds_[lo * 64 + q * 4] = make_float4(bf2f(dv[0]), bf2f(dv[1]), bf2f(dv[2]), bf2f(dv[3]));
    *(float4*)&xs_[lo * 64 + q * 4] = *(const float4*)&xg[(size_t)lo * MM + q * 4];
    *(float4*)&zs_[lo * 64 + q * 4] = *(const float4*)&zg[(size_t)lo * MM + q * 4];
  }
  for (int i = t; i < CLEN * 32; i += 256) {
    int r = i >> 5, cc = i & 31;
    bs[i] = xp[(size_t)(b * LL + l0 + r) * NN + RR + cc];
  }
  __syncthreads();
  float4 A2v = *(const float4*)&A2t[m * DD + dsub * 4];
  size_t o = ((size_t)((c * BB + b) * MM + m)) * DD + dsub * 4;
  float4 hv = *(const float4*)&h0w[o];
  float h0_ = hv.x, h1_ = hv.y, h2_ = hv.z, h3_ = hv.w;
  float Dpm = Dp[m];
  size_t idx = ((size_t)(b * LL + l0)) * MM + m;
#pragma unroll 4
  for (int lo = 0; lo < CLEN; ++lo) {
    float dtv = ds_[lo * 64 + ml];
    float xv = xs_[lo * 64 + ml];
    float zv = zs_[lo * 64 + ml];
    float4 Bv = *(const float4*)&bs[lo * 32 + dsub * 4];
    float4 Cv = *(const float4*)&bs[lo * 32 + DD + dsub * 4];
    float dtx = dtv * xv;
    h0_ = __expf(dtv * A2v.x) * h0_ + dtx * Bv.x;
    h1_ = __expf(dtv * A2v.y) * h1_ + dtx * Bv.y;
    h2_ = __expf(dtv * A2v.z) * h2_ + dtx * Bv.z;
    h3_ = __expf(dtv * A2v.w) * h3_ + dtx * Bv.w;
    float yp = h0_ * Cv.x + h1_ * Cv.y + h2_ * Cv.z + h3_ * Cv.w;
    yp += dpp_xor1(yp);
    yp += dpp_xor2(yp);
    float sig = __builtin_amdgcn_rcpf(1.f + __expf(-zv));
    if (dsub == 0)
      out[idx + (size_t)lo * MM] = (yp + Dpm * xv) * zv * sig;
  }
}

extern "C" void kernel_launch(void* const* d_in, const int* in_sizes, int n_in,
                              void* d_out, int out_size, void* d_ws, size_t ws_size,
                              hipStream_t stream) {
  const float* x = (const float*)d_in[0];
  const float* z = (const float*)d_in[1];
  const float* W = (const float*)d_in[2];
  const float* dtW = (const float*)d_in[3];
  const float* dtb = (const float*)d_in[4];
  const float* A_log = (const float*)d_in[5];
  const float* Dp = (const float*)d_in[6];
  float* out = (float*)d_out;
  float* ws = (float*)d_ws;

  k_xp<<<XP_GEMM_BLOCKS + (MM * DD / 64), 64, 0, stream>>>(x, W, A_log, ws);
  k_dt<<<(BLROWS / 16) * 8, 64, 0, stream>>>(dtW, dtb, ws);
  k_scan1<<<16 * NCH * BB, 256, 0, stream>>>(x, ws);
  k_scan2<<<128, 256, 0, stream>>>(ws);
  k_scan3<<<16 * NCH * BB, 256, 0, stream>>>(x, z, Dp, out, ws);
}